// Round 18
// baseline (146.713 us; speedup 1.0000x reference)
//
#include <hip/hip_runtime.h>
#include <hip/hip_bf16.h>
#include <cstdint>
#include <cstddef>

typedef __attribute__((ext_vector_type(8))) short short8;
typedef __attribute__((ext_vector_type(4))) short s16x4;
typedef __attribute__((ext_vector_type(4))) unsigned short u16x4;
typedef __attribute__((ext_vector_type(8))) unsigned short u16x8;
typedef __attribute__((ext_vector_type(4))) float f32x4;
typedef __attribute__((ext_vector_type(4))) unsigned int u32x4;

__device__ __forceinline__ short bfbits(float f) {
    __bf16 h = (__bf16)f;
    return __builtin_bit_cast(short, h);
}
__device__ __forceinline__ float bf2f(unsigned short b) {
    union { uint32_t u; float f; } v; v.u = ((uint32_t)b) << 16;
    return v.f;
}
__device__ __forceinline__ unsigned int pack2(float x, float y) {
    return (unsigned int)(unsigned short)bfbits(x) |
           ((unsigned int)(unsigned short)bfbits(y) << 16);
}

// ---------- kernel 0: weight transpose + bias tiling (merged prep) ----------
__global__ __launch_bounds__(256) void prep_kernel(
    const float* __restrict__ Wq, const float* __restrict__ Wk,
    const float* __restrict__ Wv, const float* __restrict__ Wg,
    const float* __restrict__ Wo, unsigned short* __restrict__ wt,
    const float* __restrict__ bias, float* __restrict__ bt)
{
    int bid = blockIdx.x;
    int tid = threadIdx.x;
    if (bid < 80) {
        int mat  = bid >> 4;
        int tile = bid & 15;
        int k0 = (tile >> 2) * 64, n0 = (tile & 3) * 64;
        const float* W = (mat==0)?Wq:(mat==1)?Wk:(mat==2)?Wv:(mat==3)?Wg:Wo;
        __shared__ unsigned short T[64][72];   // T[n][k]
        int tx = tid & 15, ty = tid >> 4;
        #pragma unroll
        for (int j = 0; j < 4; ++j) {
            int kr = ty + j*16;
            f32x4 v = *(const f32x4*)(W + (size_t)(k0+kr)*256 + n0 + tx*4);
            #pragma unroll
            for (int e = 0; e < 4; ++e) T[tx*4+e][kr] = (unsigned short)bfbits(v[e]);
        }
        __syncthreads();
        #pragma unroll
        for (int j = 0; j < 4; ++j) {
            int nr = ty + j*16;
            int kk = k0 + tx*4;
            int dstk = kk;
            if (mat == 4) {
                // sigma within each 32-block of k: 4a+e -> 8a+e (a<4), 16+4g+e -> 8g+4+e
                int a = (kk >> 2) & 7;
                int hb = kk & ~31;
                dstk = hb + ((a < 4) ? 8*a : 8*(a-4) + 4);
            }
            u16x4 st;
            #pragma unroll
            for (int e = 0; e < 4; ++e) st[e] = T[nr][tx*4+e];
            *(u16x4*)(wt + ((size_t)mat*256 + n0+nr)*256 + dstk) = st;
        }
    } else {
        int hb = bid - 80;          // 0..127 = h*16 + qt
        int h = hb >> 4, qt = hb & 15;
        int cc = tid >> 4, n = tid & 15;
        const float* src = bias + ((size_t)(h*256 + qt*16 + cc))*256 + n*16;
        float* dst = bt + ((size_t)(hb*16 + n))*256 + cc*16;
        #pragma unroll
        for (int q = 0; q < 4; ++q)
            *(f32x4*)(dst + q*4) = *(const f32x4*)(src + q*4);
    }
}

// ---------- proj K-loop, 2 col-tiles/wave (depth-1 weight prefetch) ----------
// As: 64x256 bf16 tile, row stride 512 B, byte-col XOR ((row&31)<<4).
template<int SWAP>
__device__ __forceinline__ void proj_mfma_loop2(
    const unsigned short* As, const unsigned short* Wt,
    int col0, int c, int g, f32x4 acc[4][2])
{
    short8 pb[2];
    #pragma unroll
    for (int n = 0; n < 2; ++n)
        pb[n] = *(const short8*)(Wt + (size_t)(col0 + n*16 + c) * 256 + g*8);

    #pragma unroll
    for (int step = 0; step < 8; ++step) {
        short8 b[2];
        #pragma unroll
        for (int n = 0; n < 2; ++n) b[n] = pb[n];
        if (step < 7) {
            int koff = (step + 1) * 32 + g * 8;
            #pragma unroll
            for (int n = 0; n < 2; ++n)
                pb[n] = *(const short8*)(Wt + (size_t)(col0 + n*16 + c) * 256 + koff);
        }
        short8 a[4];
        #pragma unroll
        for (int m = 0; m < 4; ++m) {
            int row = m * 16 + c;
            int off = row * 512 + ((step * 64 + g * 16) ^ ((row & 31) << 4));
            a[m] = *(const short8*)((const char*)As + off);
        }
        #pragma unroll
        for (int m = 0; m < 4; ++m)
            #pragma unroll
            for (int n = 0; n < 2; ++n) {
                if (SWAP)
                    acc[m][n] = __builtin_amdgcn_mfma_f32_16x16x32_bf16(b[n], a[m], acc[m][n], 0, 0, 0);
                else
                    acc[m][n] = __builtin_amdgcn_mfma_f32_16x16x32_bf16(a[m], b[n], acc[m][n], 0, 0, 0);
            }
    }
}

// ---------- kernel 1: projections, 3-phase pipeline (R17, best) ----------
__global__ __launch_bounds__(512, 2) void proj_kernel(
    const float* __restrict__ qx, const float* __restrict__ kx, const float* __restrict__ vx,
    const float* __restrict__ bg, const unsigned short* __restrict__ wt,
    unsigned short* __restrict__ Qa, unsigned short* __restrict__ Ka,
    unsigned short* __restrict__ Va, unsigned short* __restrict__ G)
{
    __shared__ __align__(16) unsigned short As[2][64 * 256];   // 2 x 32 KB

    int rb = blockIdx.x;
    int row0 = rb * 64;
    int tid = threadIdx.x;
    int w = tid >> 6, lane = tid & 63;
    int c = lane & 15, g = lane >> 4;
    int col0 = w * 32;
    int l32 = tid & 31, rg = tid >> 5;      // staging coords
    int r_ = row0 >> 8;
    int s0b = row0 & 255;
    int h_ = col0 >> 5;                     // one head per wave

    u32x4 pk[4], pn[4];

    // load+pack qx
    #pragma unroll
    for (int j = 0; j < 4; ++j) {
        const float* src = qx + (size_t)(row0 + j*16 + rg) * 256 + l32 * 8;
        f32x4 lo = *(const f32x4*)src;
        f32x4 hi = *(const f32x4*)(src + 4);
        pk[j][0] = pack2(lo[0], lo[1]); pk[j][1] = pack2(lo[2], lo[3]);
        pk[j][2] = pack2(hi[0], hi[1]); pk[j][3] = pack2(hi[2], hi[3]);
    }

    // ================= phase 0: Q + G from qx =================
    #pragma unroll
    for (int j = 0; j < 4; ++j) {
        int row = j*16 + rg;
        int off = row * 512 + ((l32 * 16) ^ ((row & 31) << 4));
        *(u32x4*)((char*)&As[0][0] + off) = pk[j];
    }
    // issue kx load (hides under Q+G compute)
    #pragma unroll
    for (int j = 0; j < 4; ++j) {
        const float* src = kx + (size_t)(row0 + j*16 + rg) * 256 + l32 * 8;
        f32x4 lo = *(const f32x4*)src;
        f32x4 hi = *(const f32x4*)(src + 4);
        pn[j][0] = pack2(lo[0], lo[1]); pn[j][1] = pack2(lo[2], lo[3]);
        pn[j][2] = pack2(hi[0], hi[1]); pn[j][3] = pack2(hi[2], hi[3]);
    }
    __syncthreads();
    {
        f32x4 acc[4][2];
        #pragma unroll
        for (int m = 0; m < 4; ++m)
            #pragma unroll
            for (int n = 0; n < 2; ++n) acc[m][n] = 0.0f;
        proj_mfma_loop2<1>(&As[0][0], wt, col0, c, g, acc);
        #pragma unroll
        for (int m = 0; m < 4; ++m) {
            int s_ = s0b + m * 16 + c;
            u16x8 st;
            #pragma unroll
            for (int i = 0; i < 4; ++i) {
                st[i]     = (unsigned short)bfbits(acc[m][0][i]);
                st[i + 4] = (unsigned short)bfbits(acc[m][1][i]);
            }
            *(u16x8*)(Qa + ((size_t)((r_*8 + h_)*256 + s_)) * 32 + 8*g) = st;
        }
        // G
        #pragma unroll
        for (int m = 0; m < 4; ++m)
            #pragma unroll
            for (int n = 0; n < 2; ++n) acc[m][n] = 0.0f;
        proj_mfma_loop2<1>(&As[0][0], wt + 3*65536, col0, c, g, acc);
        f32x4 bg0 = *(const f32x4*)(bg + col0 + 4*g);
        f32x4 bg1 = *(const f32x4*)(bg + col0 + 16 + 4*g);
        #pragma unroll
        for (int m = 0; m < 4; ++m) {
            int rq = row0 + m * 16 + c;
            u16x8 st;
            #pragma unroll
            for (int i = 0; i < 4; ++i) {
                float sa = 1.0f / (1.0f + __expf(-(acc[m][0][i] + bg0[i])));
                float sb = 1.0f / (1.0f + __expf(-(acc[m][1][i] + bg1[i])));
                st[i]     = (unsigned short)bfbits(sa);
                st[i + 4] = (unsigned short)bfbits(sb);
            }
            *(u16x8*)(G + (size_t)rq * 256 + col0 + 8*g) = st;
        }
    }

    // ================= phase 1: K from kx =================
    #pragma unroll
    for (int j = 0; j < 4; ++j) {
        int row = j*16 + rg;
        int off = row * 512 + ((l32 * 16) ^ ((row & 31) << 4));
        *(u32x4*)((char*)&As[1][0] + off) = pn[j];
    }
    // issue vx load (hides under K compute)
    #pragma unroll
    for (int j = 0; j < 4; ++j) {
        const float* src = vx + (size_t)(row0 + j*16 + rg) * 256 + l32 * 8;
        f32x4 lo = *(const f32x4*)src;
        f32x4 hi = *(const f32x4*)(src + 4);
        pk[j][0] = pack2(lo[0], lo[1]); pk[j][1] = pack2(lo[2], lo[3]);
        pk[j][2] = pack2(hi[0], hi[1]); pk[j][3] = pack2(hi[2], hi[3]);
    }
    __syncthreads();
    {
        f32x4 acc[4][2];
        #pragma unroll
        for (int m = 0; m < 4; ++m)
            #pragma unroll
            for (int n = 0; n < 2; ++n) acc[m][n] = 0.0f;
        proj_mfma_loop2<1>(&As[1][0], wt + 65536, col0, c, g, acc);
        #pragma unroll
        for (int m = 0; m < 4; ++m) {
            int s_ = s0b + m * 16 + c;
            u16x8 st;
            #pragma unroll
            for (int i = 0; i < 4; ++i) {
                st[i]     = (unsigned short)bfbits(acc[m][0][i]);
                st[i + 4] = (unsigned short)bfbits(acc[m][1][i]);
            }
            *(u16x8*)(Ka + ((size_t)((r_*8 + h_)*256 + s_)) * 32 + 8*g) = st;
        }
    }

    // ================= phase 2: V from vx =================
    #pragma unroll
    for (int j = 0; j < 4; ++j) {
        int row = j*16 + rg;
        int off = row * 512 + ((l32 * 16) ^ ((row & 31) << 4));
        *(u32x4*)((char*)&As[0][0] + off) = pk[j];
    }
    __syncthreads();
    {
        f32x4 acc[4][2];
        #pragma unroll
        for (int m = 0; m < 4; ++m)
            #pragma unroll
            for (int n = 0; n < 2; ++n) acc[m][n] = 0.0f;
        proj_mfma_loop2<0>(&As[0][0], wt + 2*65536, col0, c, g, acc);
        #pragma unroll
        for (int n = 0; n < 2; ++n) {
            int d_ = n*16 + c;
            size_t rowbase = ((size_t)((r_*8 + h_)*32 + d_)) * 256;
            #pragma unroll
            for (int p = 0; p < 2; ++p) {    // m-pairs (0,1),(2,3) -> tau slots
                u16x8 st;
                #pragma unroll
                for (int i = 0; i < 4; ++i) {
                    st[i]     = (unsigned short)bfbits(acc[2*p][n][i]);
                    st[i + 4] = (unsigned short)bfbits(acc[2*p+1][n][i]);
                }
                *(u16x8*)(Va + rowbase + s0b + 32*p + 8*g) = st;
            }
        }
    }
}

// ---------- kernel 2: fused attention + output projection ----------
// Block (r, qb): 64 q-rows, 4 waves x 16 rows. Loop over 8 heads:
// stage K_h/V_h -> swapped QK^T -> online exp -> PV -> gate -> the stored-og
// bf16 vector IS the oproj A-fragment (sigma layout) -> acc[n] += mfma(Wo,og).
// acc initialized with bo; final coalesced f32x4 stores. No og buffer.
__global__ __launch_bounds__(256, 3) void attn_oproj_kernel(
    const unsigned short* __restrict__ Qa, const unsigned short* __restrict__ Ka,
    const unsigned short* __restrict__ Va, const unsigned short* __restrict__ G,
    const float* __restrict__ bt, const unsigned short* __restrict__ wt_o,
    const float* __restrict__ bo, float* __restrict__ out)
{
    __shared__ __align__(16) unsigned short Ks[256 * 40];  // [s][d'] pad 40
    __shared__ __align__(16) unsigned short Vs[32 * 264];  // [d][s'=slot] pad 264

    int bx = blockIdx.x;            // 512 = r(128) x qb(4)
    int r = bx >> 2, qb = bx & 3;
    int tid = threadIdx.x;          // 256 threads, 4 waves
    int w = tid >> 6, lane = tid & 63;
    int c = lane & 15, g = lane >> 4;
    int qrow = qb * 64 + w * 16;
    int qt = qb * 4 + w;
    const float nrmv = 0.17677669529663687f;

    // out accumulator, initialized with bias bo (added once)
    f32x4 acc[16];
    #pragma unroll
    for (int n = 0; n < 16; ++n)
        acc[n] = *(const f32x4*)(bo + n*16 + 4*g);

    #pragma unroll 1
    for (int h = 0; h < 8; ++h) {
        size_t base = ((size_t)(r*8 + h)) * 8192;

        // stage K_h (padded) and V_h (tau slot order), 256 threads x 4 passes
        #pragma unroll
        for (int j = 0; j < 4; ++j) {
            int idx8 = (tid + j*256) * 8;
            int s_ = idx8 >> 5, d_ = idx8 & 31;
            *(short8*)(&Ks[s_*40 + d_]) = *(const short8*)(Ka + base + idx8);
        }
        #pragma unroll
        for (int j = 0; j < 4; ++j) {
            int idx8 = (tid + j*256) * 8;
            int d_ = idx8 >> 8, s0 = idx8 & 255;
            *(short8*)(&Vs[d_*264 + s0]) = *(const short8*)(Va + base + idx8);
        }
        __syncthreads();

        short8 qf = *(const short8*)(Qa + base + (size_t)(qrow + c)*32 + g*8);
        const float* btt = bt + (size_t)h*65536 + (size_t)qt*4096 + (c*4 + g)*4;

        f32x4 o0 = 0.0f, o1 = 0.0f;
        float sum = 0.f;
        #pragma unroll
        for (int t = 0; t < 8; ++t) {
            int n0 = 2*t, n1 = 2*t + 1;
            short8 kf0 = *(const short8*)(&Ks[(n0*16 + c)*40 + g*8]);
            short8 kf1 = *(const short8*)(&Ks[(n1*16 + c)*40 + g*8]);
            f32x4 bv0 = *(const f32x4*)(btt + n0*256);
            f32x4 bv1 = *(const f32x4*)(btt + n1*256);
            f32x4 z = 0.0f;
            f32x4 s0 = __builtin_amdgcn_mfma_f32_16x16x32_bf16(kf0, qf, z, 0, 0, 0);
            f32x4 s1 = __builtin_amdgcn_mfma_f32_16x16x32_bf16(kf1, qf, z, 0, 0, 0);
            float e0 = __expf(fmaf(s0[0], nrmv, bv0[0]));
            float e1 = __expf(fmaf(s0[1], nrmv, bv0[1]));
            float e2 = __expf(fmaf(s0[2], nrmv, bv0[2]));
            float e3 = __expf(fmaf(s0[3], nrmv, bv0[3]));
            float e4 = __expf(fmaf(s1[0], nrmv, bv1[0]));
            float e5 = __expf(fmaf(s1[1], nrmv, bv1[1]));
            float e6 = __expf(fmaf(s1[2], nrmv, bv1[2]));
            float e7 = __expf(fmaf(s1[3], nrmv, bv1[3]));
            sum += ((e0+e1)+(e2+e3)) + ((e4+e5)+(e6+e7));
            u32x4 aw;
            aw[0] = pack2(e0, e1); aw[1] = pack2(e2, e3);
            aw[2] = pack2(e4, e5); aw[3] = pack2(e6, e7);
            short8 pfrag = __builtin_bit_cast(short8, aw);
            short8 va0 = *(const short8*)(&Vs[(c)*264      + t*32 + g*8]);
            short8 va1 = *(const short8*)(&Vs[(16 + c)*264 + t*32 + g*8]);
            o0 = __builtin_amdgcn_mfma_f32_16x16x32_bf16(va0, pfrag, o0, 0, 0, 0);
            o1 = __builtin_amdgcn_mfma_f32_16x16x32_bf16(va1, pfrag, o1, 0, 0, 0);
        }
        sum += __shfl_xor(sum, 16);
        sum += __shfl_xor(sum, 32);
        float inv = 1.0f / sum;

        // gate; build og A-fragment in-register (sigma layout == k-slot order)
        size_t orow = ((size_t)(r*256 + qrow + c)) * 256 + h*32 + 8*g;
        u16x8 gv = *(const u16x8*)(G + orow);
        u16x8 av;
        #pragma unroll
        for (int i = 0; i < 4; ++i) {
            av[i]     = (unsigned short)bfbits(o0[i] * inv * bf2f(gv[i]));
            av[i + 4] = (unsigned short)bfbits(o1[i] * inv * bf2f(gv[i + 4]));
        }
        short8 afrag = __builtin_bit_cast(short8, av);

        // oproj accumulate: acc[n] += Wo_h^T-frag * og-frag (swapped)
        const unsigned short* wo = wt_o + 32*h + g*8;
        #pragma unroll
        for (int n = 0; n < 16; ++n) {
            short8 b = *(const short8*)(wo + (size_t)(n*16 + c) * 256);
            acc[n] = __builtin_amdgcn_mfma_f32_16x16x32_bf16(b, afrag, acc[n], 0, 0, 0);
        }
        __syncthreads();   // protect Ks/Vs before next head's staging
    }

    // store: lane (c,g), tile n -> out[q=qrow+c][n*16+4g .. +3] (f32x4)
    float* orow_out = out + (size_t)(r*256 + qrow + c) * 256 + 4*g;
    #pragma unroll
    for (int n = 0; n < 16; ++n)
        *(f32x4*)(orow_out + n*16) = acc[n];
}

extern "C" void kernel_launch(void* const* d_in, const int* in_sizes, int n_in,
                              void* d_out, int out_size, void* d_ws, size_t ws_size,
                              hipStream_t stream) {
    const float* qx   = (const float*)d_in[0];
    const float* kx   = (const float*)d_in[1];
    const float* vx   = (const float*)d_in[2];
    const float* bias = (const float*)d_in[3];
    const float* Wq   = (const float*)d_in[4];
    const float* Wk   = (const float*)d_in[5];
    const float* Wv   = (const float*)d_in[6];
    const float* Wo   = (const float*)d_in[7];
    const float* bo   = (const float*)d_in[8];
    const float* Wg   = (const float*)d_in[9];
    const float* bg   = (const float*)d_in[10];

    uint8_t* ws = (uint8_t*)d_ws;
    unsigned short* wt = (unsigned short*)ws;                         // 640 KB
    unsigned short* Qa = (unsigned short*)(ws + (1u<<20));
    unsigned short* Ka = (unsigned short*)(ws + (1u<<20) + 1u*(1u<<24));
    unsigned short* Va = (unsigned short*)(ws + (1u<<20) + 2u*(1u<<24));
    unsigned short* G  = (unsigned short*)(ws + (1u<<20) + 3u*(1u<<24));
    float*          bt = (float*)        (ws + (1u<<20) + 5u*(1u<<24)); // 2 MB

    hipLaunchKernelGGL(prep_kernel, dim3(208), dim3(256), 0, stream,
                       Wq, Wk, Wv, Wg, Wo, wt, bias, bt);
    hipLaunchKernelGGL(proj_kernel, dim3(512), dim3(512), 0, stream,
                       qx, kx, vx, bg, wt, Qa, Ka, Va, G);
    hipLaunchKernelGGL(attn_oproj_kernel, dim3(512), dim3(256), 0, stream,
                       Qa, Ka, Va, G, bt, wt + 4*65536, bo, (float*)d_out);
}

// Round 19
// 120.376 us; speedup vs baseline: 1.2188x; 1.2188x over previous
//
#include <hip/hip_runtime.h>
#include <hip/hip_bf16.h>
#include <cstdint>
#include <cstddef>

typedef __attribute__((ext_vector_type(8))) short short8;
typedef __attribute__((ext_vector_type(4))) short s16x4;
typedef __attribute__((ext_vector_type(4))) unsigned short u16x4;
typedef __attribute__((ext_vector_type(8))) unsigned short u16x8;
typedef __attribute__((ext_vector_type(4))) float f32x4;
typedef __attribute__((ext_vector_type(4))) unsigned int u32x4;

__device__ __forceinline__ short bfbits(float f) {
    __bf16 h = (__bf16)f;
    return __builtin_bit_cast(short, h);
}
__device__ __forceinline__ float bf2f(unsigned short b) {
    union { uint32_t u; float f; } v; v.u = ((uint32_t)b) << 16;
    return v.f;
}
__device__ __forceinline__ unsigned int pack2(float x, float y) {
    return (unsigned int)(unsigned short)bfbits(x) |
           ((unsigned int)(unsigned short)bfbits(y) << 16);
}

// ---------- kernel 0: weight transpose + bias tiling (merged prep) ----------
__global__ __launch_bounds__(256) void prep_kernel(
    const float* __restrict__ Wq, const float* __restrict__ Wk,
    const float* __restrict__ Wv, const float* __restrict__ Wg,
    const float* __restrict__ Wo, unsigned short* __restrict__ wt,
    const float* __restrict__ bias, float* __restrict__ bt)
{
    int bid = blockIdx.x;
    int tid = threadIdx.x;
    if (bid < 80) {
        int mat  = bid >> 4;
        int tile = bid & 15;
        int k0 = (tile >> 2) * 64, n0 = (tile & 3) * 64;
        const float* W = (mat==0)?Wq:(mat==1)?Wk:(mat==2)?Wv:(mat==3)?Wg:Wo;
        __shared__ unsigned short T[64][72];   // T[n][k]
        int tx = tid & 15, ty = tid >> 4;
        #pragma unroll
        for (int j = 0; j < 4; ++j) {
            int kr = ty + j*16;
            f32x4 v = *(const f32x4*)(W + (size_t)(k0+kr)*256 + n0 + tx*4);
            #pragma unroll
            for (int e = 0; e < 4; ++e) T[tx*4+e][kr] = (unsigned short)bfbits(v[e]);
        }
        __syncthreads();
        #pragma unroll
        for (int j = 0; j < 4; ++j) {
            int nr = ty + j*16;
            int kk = k0 + tx*4;
            int dstk = kk;
            if (mat == 4) {
                // sigma within each 32-block of k: 4a+e -> 8a+e (a<4), 16+4g+e -> 8g+4+e
                int a = (kk >> 2) & 7;
                int hb = kk & ~31;
                dstk = hb + ((a < 4) ? 8*a : 8*(a-4) + 4);
            }
            u16x4 st;
            #pragma unroll
            for (int e = 0; e < 4; ++e) st[e] = T[nr][tx*4+e];
            *(u16x4*)(wt + ((size_t)mat*256 + n0+nr)*256 + dstk) = st;
        }
    } else {
        int hb = bid - 80;          // 0..127 = h*16 + qt
        int h = hb >> 4, qt = hb & 15;
        int cc = tid >> 4, n = tid & 15;
        const float* src = bias + ((size_t)(h*256 + qt*16 + cc))*256 + n*16;
        float* dst = bt + ((size_t)(hb*16 + n))*256 + cc*16;
        #pragma unroll
        for (int q = 0; q < 4; ++q)
            *(f32x4*)(dst + q*4) = *(const f32x4*)(src + q*4);
    }
}

// ---------- proj K-loop, 2 col-tiles/wave (depth-1 weight prefetch) ----------
// As: 64x256 bf16 tile, row stride 512 B, byte-col XOR ((row&31)<<4).
template<int SWAP>
__device__ __forceinline__ void proj_mfma_loop2(
    const unsigned short* As, const unsigned short* Wt,
    int col0, int c, int g, f32x4 acc[4][2])
{
    short8 pb[2];
    #pragma unroll
    for (int n = 0; n < 2; ++n)
        pb[n] = *(const short8*)(Wt + (size_t)(col0 + n*16 + c) * 256 + g*8);

    #pragma unroll
    for (int step = 0; step < 8; ++step) {
        short8 b[2];
        #pragma unroll
        for (int n = 0; n < 2; ++n) b[n] = pb[n];
        if (step < 7) {
            int koff = (step + 1) * 32 + g * 8;
            #pragma unroll
            for (int n = 0; n < 2; ++n)
                pb[n] = *(const short8*)(Wt + (size_t)(col0 + n*16 + c) * 256 + koff);
        }
        short8 a[4];
        #pragma unroll
        for (int m = 0; m < 4; ++m) {
            int row = m * 16 + c;
            int off = row * 512 + ((step * 64 + g * 16) ^ ((row & 31) << 4));
            a[m] = *(const short8*)((const char*)As + off);
        }
        #pragma unroll
        for (int m = 0; m < 4; ++m)
            #pragma unroll
            for (int n = 0; n < 2; ++n) {
                if (SWAP)
                    acc[m][n] = __builtin_amdgcn_mfma_f32_16x16x32_bf16(b[n], a[m], acc[m][n], 0, 0, 0);
                else
                    acc[m][n] = __builtin_amdgcn_mfma_f32_16x16x32_bf16(a[m], b[n], acc[m][n], 0, 0, 0);
            }
    }
}

// ---------- kernel 1: projections, 3-phase pipeline (R17, best) ----------
__global__ __launch_bounds__(512, 2) void proj_kernel(
    const float* __restrict__ qx, const float* __restrict__ kx, const float* __restrict__ vx,
    const float* __restrict__ bg, const unsigned short* __restrict__ wt,
    unsigned short* __restrict__ Qa, unsigned short* __restrict__ Ka,
    unsigned short* __restrict__ Va, unsigned short* __restrict__ G)
{
    __shared__ __align__(16) unsigned short As[2][64 * 256];   // 2 x 32 KB

    int rb = blockIdx.x;
    int row0 = rb * 64;
    int tid = threadIdx.x;
    int w = tid >> 6, lane = tid & 63;
    int c = lane & 15, g = lane >> 4;
    int col0 = w * 32;
    int l32 = tid & 31, rg = tid >> 5;      // staging coords
    int r_ = row0 >> 8;
    int s0b = row0 & 255;
    int h_ = col0 >> 5;                     // one head per wave

    u32x4 pk[4], pn[4];

    // load+pack qx
    #pragma unroll
    for (int j = 0; j < 4; ++j) {
        const float* src = qx + (size_t)(row0 + j*16 + rg) * 256 + l32 * 8;
        f32x4 lo = *(const f32x4*)src;
        f32x4 hi = *(const f32x4*)(src + 4);
        pk[j][0] = pack2(lo[0], lo[1]); pk[j][1] = pack2(lo[2], lo[3]);
        pk[j][2] = pack2(hi[0], hi[1]); pk[j][3] = pack2(hi[2], hi[3]);
    }

    // ================= phase 0: Q + G from qx =================
    #pragma unroll
    for (int j = 0; j < 4; ++j) {
        int row = j*16 + rg;
        int off = row * 512 + ((l32 * 16) ^ ((row & 31) << 4));
        *(u32x4*)((char*)&As[0][0] + off) = pk[j];
    }
    // issue kx load (hides under Q+G compute)
    #pragma unroll
    for (int j = 0; j < 4; ++j) {
        const float* src = kx + (size_t)(row0 + j*16 + rg) * 256 + l32 * 8;
        f32x4 lo = *(const f32x4*)src;
        f32x4 hi = *(const f32x4*)(src + 4);
        pn[j][0] = pack2(lo[0], lo[1]); pn[j][1] = pack2(lo[2], lo[3]);
        pn[j][2] = pack2(hi[0], hi[1]); pn[j][3] = pack2(hi[2], hi[3]);
    }
    __syncthreads();
    {
        f32x4 acc[4][2];
        #pragma unroll
        for (int m = 0; m < 4; ++m)
            #pragma unroll
            for (int n = 0; n < 2; ++n) acc[m][n] = 0.0f;
        proj_mfma_loop2<1>(&As[0][0], wt, col0, c, g, acc);
        #pragma unroll
        for (int m = 0; m < 4; ++m) {
            int s_ = s0b + m * 16 + c;
            u16x8 st;
            #pragma unroll
            for (int i = 0; i < 4; ++i) {
                st[i]     = (unsigned short)bfbits(acc[m][0][i]);
                st[i + 4] = (unsigned short)bfbits(acc[m][1][i]);
            }
            *(u16x8*)(Qa + ((size_t)((r_*8 + h_)*256 + s_)) * 32 + 8*g) = st;
        }
        // G
        #pragma unroll
        for (int m = 0; m < 4; ++m)
            #pragma unroll
            for (int n = 0; n < 2; ++n) acc[m][n] = 0.0f;
        proj_mfma_loop2<1>(&As[0][0], wt + 3*65536, col0, c, g, acc);
        f32x4 bg0 = *(const f32x4*)(bg + col0 + 4*g);
        f32x4 bg1 = *(const f32x4*)(bg + col0 + 16 + 4*g);
        #pragma unroll
        for (int m = 0; m < 4; ++m) {
            int rq = row0 + m * 16 + c;
            u16x8 st;
            #pragma unroll
            for (int i = 0; i < 4; ++i) {
                float sa = 1.0f / (1.0f + __expf(-(acc[m][0][i] + bg0[i])));
                float sb = 1.0f / (1.0f + __expf(-(acc[m][1][i] + bg1[i])));
                st[i]     = (unsigned short)bfbits(sa);
                st[i + 4] = (unsigned short)bfbits(sb);
            }
            *(u16x8*)(G + (size_t)rq * 256 + col0 + 8*g) = st;
        }
    }

    // ================= phase 1: K from kx =================
    #pragma unroll
    for (int j = 0; j < 4; ++j) {
        int row = j*16 + rg;
        int off = row * 512 + ((l32 * 16) ^ ((row & 31) << 4));
        *(u32x4*)((char*)&As[1][0] + off) = pn[j];
    }
    // issue vx load (hides under K compute)
    #pragma unroll
    for (int j = 0; j < 4; ++j) {
        const float* src = vx + (size_t)(row0 + j*16 + rg) * 256 + l32 * 8;
        f32x4 lo = *(const f32x4*)src;
        f32x4 hi = *(const f32x4*)(src + 4);
        pk[j][0] = pack2(lo[0], lo[1]); pk[j][1] = pack2(lo[2], lo[3]);
        pk[j][2] = pack2(hi[0], hi[1]); pk[j][3] = pack2(hi[2], hi[3]);
    }
    __syncthreads();
    {
        f32x4 acc[4][2];
        #pragma unroll
        for (int m = 0; m < 4; ++m)
            #pragma unroll
            for (int n = 0; n < 2; ++n) acc[m][n] = 0.0f;
        proj_mfma_loop2<1>(&As[1][0], wt + 65536, col0, c, g, acc);
        #pragma unroll
        for (int m = 0; m < 4; ++m) {
            int s_ = s0b + m * 16 + c;
            u16x8 st;
            #pragma unroll
            for (int i = 0; i < 4; ++i) {
                st[i]     = (unsigned short)bfbits(acc[m][0][i]);
                st[i + 4] = (unsigned short)bfbits(acc[m][1][i]);
            }
            *(u16x8*)(Ka + ((size_t)((r_*8 + h_)*256 + s_)) * 32 + 8*g) = st;
        }
    }

    // ================= phase 2: V from vx =================
    #pragma unroll
    for (int j = 0; j < 4; ++j) {
        int row = j*16 + rg;
        int off = row * 512 + ((l32 * 16) ^ ((row & 31) << 4));
        *(u32x4*)((char*)&As[0][0] + off) = pk[j];
    }
    __syncthreads();
    {
        f32x4 acc[4][2];
        #pragma unroll
        for (int m = 0; m < 4; ++m)
            #pragma unroll
            for (int n = 0; n < 2; ++n) acc[m][n] = 0.0f;
        proj_mfma_loop2<0>(&As[0][0], wt + 2*65536, col0, c, g, acc);
        #pragma unroll
        for (int n = 0; n < 2; ++n) {
            int d_ = n*16 + c;               // (col0+n*16)&31 + c, col0 mult of 32
            size_t rowbase = ((size_t)((r_*8 + h_)*32 + d_)) * 256;
            #pragma unroll
            for (int p = 0; p < 2; ++p) {    // m-pairs (0,1),(2,3) -> tau slots
                u16x8 st;
                #pragma unroll
                for (int i = 0; i < 4; ++i) {
                    st[i]     = (unsigned short)bfbits(acc[2*p][n][i]);
                    st[i + 4] = (unsigned short)bfbits(acc[2*p+1][n][i]);
                }
                *(u16x8*)(Va + rowbase + s0b + 32*p + 8*g) = st;
            }
        }
    }
}

// ---------- kernel 2: attention, one block per (r,h), K/V in LDS ----------
__global__ __launch_bounds__(512) void attn_kernel(
    const unsigned short* __restrict__ Qa, const unsigned short* __restrict__ Ka,
    const unsigned short* __restrict__ Va, const unsigned short* __restrict__ G,
    const float* __restrict__ bt, unsigned short* __restrict__ og)
{
    __shared__ __align__(16) unsigned short Ks[256 * 40];  // [s][d'] pad 40
    __shared__ __align__(16) unsigned short Vs[32 * 264];  // [d][s'=slot] pad 264

    int rh = blockIdx.x;            // 0..1023
    int r = rh >> 3, h = rh & 7;
    int tid = threadIdx.x;          // 512 threads
    int w = tid >> 6, lane = tid & 63;
    int c = lane & 15, g = lane >> 4;
    size_t base = (size_t)rh * 8192;

    #pragma unroll
    for (int j = 0; j < 2; ++j) {
        int idx8 = (tid + j*512) * 8;
        int s_ = idx8 >> 5, d_ = idx8 & 31;
        short8 v = *(const short8*)(Ka + base + idx8);
        *(short8*)(&Ks[s_*40 + d_]) = v;
    }
    #pragma unroll
    for (int j = 0; j < 2; ++j) {
        int idx8 = (tid + j*512) * 8;
        int d_ = idx8 >> 8, s0 = idx8 & 255;
        short8 v = *(const short8*)(Va + base + idx8);
        *(short8*)(&Vs[d_*264 + s0]) = v;
    }
    __syncthreads();

    const float* bth = bt + (size_t)h * 65536;
    const float nrmv = 0.17677669529663687f;

    #pragma unroll 1
    for (int qq = 0; qq < 2; ++qq) {
        int qt = w*2 + qq;                 // 0..15
        int qrow = qt * 16;
        short8 qf = *(const short8*)(Qa + base + (size_t)(qrow + c)*32 + g*8);
        const float* btt = bth + (size_t)qt*4096 + (c*4 + g)*4;

        f32x4 o0 = 0.0f, o1 = 0.0f;
        float sum = 0.f;
        #pragma unroll
        for (int t = 0; t < 8; ++t) {
            int n0 = 2*t, n1 = 2*t + 1;
            short8 kf0 = *(const short8*)(&Ks[(n0*16 + c)*40 + g*8]);
            short8 kf1 = *(const short8*)(&Ks[(n1*16 + c)*40 + g*8]);
            f32x4 bv0 = *(const f32x4*)(btt + n0*256);
            f32x4 bv1 = *(const f32x4*)(btt + n1*256);
            f32x4 z = 0.0f;
            f32x4 s0 = __builtin_amdgcn_mfma_f32_16x16x32_bf16(kf0, qf, z, 0, 0, 0);
            f32x4 s1 = __builtin_amdgcn_mfma_f32_16x16x32_bf16(kf1, qf, z, 0, 0, 0);
            float e0 = __expf(fmaf(s0[0], nrmv, bv0[0]));
            float e1 = __expf(fmaf(s0[1], nrmv, bv0[1]));
            float e2 = __expf(fmaf(s0[2], nrmv, bv0[2]));
            float e3 = __expf(fmaf(s0[3], nrmv, bv0[3]));
            float e4 = __expf(fmaf(s1[0], nrmv, bv1[0]));
            float e5 = __expf(fmaf(s1[1], nrmv, bv1[1]));
            float e6 = __expf(fmaf(s1[2], nrmv, bv1[2]));
            float e7 = __expf(fmaf(s1[3], nrmv, bv1[3]));
            sum += ((e0+e1)+(e2+e3)) + ((e4+e5)+(e6+e7));
            u32x4 aw;
            aw[0] = pack2(e0, e1); aw[1] = pack2(e2, e3);
            aw[2] = pack2(e4, e5); aw[3] = pack2(e6, e7);
            short8 pfrag = __builtin_bit_cast(short8, aw);
            short8 va0 = *(const short8*)(&Vs[(c)*264      + t*32 + g*8]);
            short8 va1 = *(const short8*)(&Vs[(16 + c)*264 + t*32 + g*8]);
            o0 = __builtin_amdgcn_mfma_f32_16x16x32_bf16(va0, pfrag, o0, 0, 0, 0);
            o1 = __builtin_amdgcn_mfma_f32_16x16x32_bf16(va1, pfrag, o1, 0, 0, 0);
        }
        sum += __shfl_xor(sum, 16);
        sum += __shfl_xor(sum, 32);
        float inv = 1.0f / sum;

        size_t orow = ((size_t)(r*256 + qrow + c)) * 256 + h*32 + 8*g;
        u16x8 gv = *(const u16x8*)(G + orow);
        u16x8 st;
        #pragma unroll
        for (int i = 0; i < 4; ++i) {
            st[i]     = (unsigned short)bfbits(o0[i] * inv * bf2f(gv[i]));
            st[i + 4] = (unsigned short)bfbits(o1[i] * inv * bf2f(gv[i + 4]));
        }
        *(u16x8*)(og + orow) = st;
    }
}

// ---------- oproj K-loop (As: 64x256 swizzled tile, swapped) ----------
__device__ __forceinline__ void proj_mfma_loop_swap(
    const unsigned short* As, const unsigned short* Wt,
    int col0, int c, int g, f32x4 acc[4][4])
{
    short8 pb[4];
    #pragma unroll
    for (int n = 0; n < 4; ++n)
        pb[n] = *(const short8*)(Wt + (size_t)(col0 + n*16 + c) * 256 + g*8);

    #pragma unroll
    for (int step = 0; step < 8; ++step) {
        short8 b[4];
        #pragma unroll
        for (int n = 0; n < 4; ++n) b[n] = pb[n];
        if (step < 7) {
            int koff = (step + 1) * 32 + g * 8;
            #pragma unroll
            for (int n = 0; n < 4; ++n)
                pb[n] = *(const short8*)(Wt + (size_t)(col0 + n*16 + c) * 256 + koff);
        }
        short8 a[4];
        #pragma unroll
        for (int m = 0; m < 4; ++m) {
            int row = m * 16 + c;
            int off = row * 512 + ((step * 64 + g * 16) ^ ((row & 31) << 4));
            a[m] = *(const short8*)((const char*)As + off);
        }
        #pragma unroll
        for (int m = 0; m < 4; ++m)
            #pragma unroll
            for (int n = 0; n < 4; ++n)
                acc[m][n] = __builtin_amdgcn_mfma_f32_16x16x32_bf16(b[n], a[m], acc[m][n], 0, 0, 0);
    }
}

// ---------- kernel 3: output projection (LDS-staged og, swapped MFMA) ----------
__global__ __launch_bounds__(256) void oproj_kernel(
    const unsigned short* __restrict__ og, const unsigned short* __restrict__ wt_o,
    const float* __restrict__ bo, float* __restrict__ out)
{
    __shared__ __align__(16) unsigned short As[64 * 256];

    int row0 = blockIdx.x * 64;
    int tid = threadIdx.x;
    int lane = tid & 63;
    int c = lane & 15, g = lane >> 4;
    int col0 = (tid >> 6) * 64;

    #pragma unroll
    for (int j = 0; j < 8; ++j) {
        int idx = tid * 8 + j * 2048;
        int row = idx >> 8;
        int colB = (idx & 255) * 2;
        short8 v = *(const short8*)(og + (size_t)(row0 + row) * 256 + (idx & 255));
        int off = row * 512 + (colB ^ ((row & 31) << 4));
        *(short8*)((char*)As + off) = v;
    }
    __syncthreads();

    f32x4 acc[4][4];
    #pragma unroll
    for (int m = 0; m < 4; ++m)
        #pragma unroll
        for (int n = 0; n < 4; ++n)
            acc[m][n] = 0.0f;

    proj_mfma_loop_swap(As, wt_o, col0, c, g, acc);

    #pragma unroll
    for (int n = 0; n < 4; ++n) {
        int colb = col0 + n * 16 + 4 * g;
        f32x4 bov = *(const f32x4*)(bo + colb);
        #pragma unroll
        for (int m = 0; m < 4; ++m) {
            int row = row0 + m * 16 + c;
            f32x4 st = acc[m][n] + bov;
            *(f32x4*)(out + (size_t)row * 256 + colb) = st;
        }
    }
}

extern "C" void kernel_launch(void* const* d_in, const int* in_sizes, int n_in,
                              void* d_out, int out_size, void* d_ws, size_t ws_size,
                              hipStream_t stream) {
    const float* qx   = (const float*)d_in[0];
    const float* kx   = (const float*)d_in[1];
    const float* vx   = (const float*)d_in[2];
    const float* bias = (const float*)d_in[3];
    const float* Wq   = (const float*)d_in[4];
    const float* Wk   = (const float*)d_in[5];
    const float* Wv   = (const float*)d_in[6];
    const float* Wo   = (const float*)d_in[7];
    const float* bo   = (const float*)d_in[8];
    const float* Wg   = (const float*)d_in[9];
    const float* bg   = (const float*)d_in[10];

    uint8_t* ws = (uint8_t*)d_ws;
    unsigned short* wt = (unsigned short*)ws;                         // 640 KB
    unsigned short* Qa = (unsigned short*)(ws + (1u<<20));
    unsigned short* Ka = (unsigned short*)(ws + (1u<<20) + 1u*(1u<<24));
    unsigned short* Va = (unsigned short*)(ws + (1u<<20) + 2u*(1u<<24));
    unsigned short* G  = (unsigned short*)(ws + (1u<<20) + 3u*(1u<<24));
    unsigned short* og = (unsigned short*)(ws + (1u<<20) + 4u*(1u<<24));
    float*          bt = (float*)        (ws + (1u<<20) + 5u*(1u<<24)); // 2 MB

    hipLaunchKernelGGL(prep_kernel, dim3(208), dim3(256), 0, stream,
                       Wq, Wk, Wv, Wg, Wo, wt, bias, bt);
    hipLaunchKernelGGL(proj_kernel, dim3(512), dim3(512), 0, stream,
                       qx, kx, vx, bg, wt, Qa, Ka, Va, G);
    hipLaunchKernelGGL(attn_kernel, dim3(1024), dim3(512), 0, stream,
                       Qa, Ka, Va, G, bt, og);
    hipLaunchKernelGGL(oproj_kernel, dim3(512), dim3(256), 0, stream,
                       og, wt + 4*65536, bo, (float*)d_out);
}

// Round 20
// 119.918 us; speedup vs baseline: 1.2234x; 1.0038x over previous
//
#include <hip/hip_runtime.h>
#include <hip/hip_bf16.h>
#include <cstdint>
#include <cstddef>

typedef __attribute__((ext_vector_type(8))) short short8;
typedef __attribute__((ext_vector_type(4))) short s16x4;
typedef __attribute__((ext_vector_type(4))) unsigned short u16x4;
typedef __attribute__((ext_vector_type(8))) unsigned short u16x8;
typedef __attribute__((ext_vector_type(4))) float f32x4;
typedef __attribute__((ext_vector_type(4))) unsigned int u32x4;

__device__ __forceinline__ short bfbits(float f) {
    __bf16 h = (__bf16)f;
    return __builtin_bit_cast(short, h);
}
__device__ __forceinline__ float bf2f(unsigned short b) {
    union { uint32_t u; float f; } v; v.u = ((uint32_t)b) << 16;
    return v.f;
}
__device__ __forceinline__ unsigned int pack2(float x, float y) {
    return (unsigned int)(unsigned short)bfbits(x) |
           ((unsigned int)(unsigned short)bfbits(y) << 16);
}

// lgkmcnt-only barrier: makes ds_writes visible without draining vmcnt,
// so global loads issued before it stay in flight across the barrier (T4).
__device__ __forceinline__ void barrier_lgkm_only() {
    asm volatile("s_waitcnt lgkmcnt(0)" ::: "memory");
    __builtin_amdgcn_s_barrier();
}

// ---------- kernel 0: weight transpose + bias tiling (merged prep) ----------
__global__ __launch_bounds__(256) void prep_kernel(
    const float* __restrict__ Wq, const float* __restrict__ Wk,
    const float* __restrict__ Wv, const float* __restrict__ Wg,
    const float* __restrict__ Wo, unsigned short* __restrict__ wt,
    const float* __restrict__ bias, float* __restrict__ bt)
{
    int bid = blockIdx.x;
    int tid = threadIdx.x;
    if (bid < 80) {
        int mat  = bid >> 4;
        int tile = bid & 15;
        int k0 = (tile >> 2) * 64, n0 = (tile & 3) * 64;
        const float* W = (mat==0)?Wq:(mat==1)?Wk:(mat==2)?Wv:(mat==3)?Wg:Wo;
        __shared__ unsigned short T[64][72];   // T[n][k]
        int tx = tid & 15, ty = tid >> 4;
        #pragma unroll
        for (int j = 0; j < 4; ++j) {
            int kr = ty + j*16;
            f32x4 v = *(const f32x4*)(W + (size_t)(k0+kr)*256 + n0 + tx*4);
            #pragma unroll
            for (int e = 0; e < 4; ++e) T[tx*4+e][kr] = (unsigned short)bfbits(v[e]);
        }
        __syncthreads();
        #pragma unroll
        for (int j = 0; j < 4; ++j) {
            int nr = ty + j*16;
            int kk = k0 + tx*4;
            int dstk = kk;
            if (mat == 4) {
                // sigma within each 32-block of k: 4a+e -> 8a+e (a<4), 16+4g+e -> 8g+4+e
                int a = (kk >> 2) & 7;
                int hb = kk & ~31;
                dstk = hb + ((a < 4) ? 8*a : 8*(a-4) + 4);
            }
            u16x4 st;
            #pragma unroll
            for (int e = 0; e < 4; ++e) st[e] = T[nr][tx*4+e];
            *(u16x4*)(wt + ((size_t)mat*256 + n0+nr)*256 + dstk) = st;
        }
    } else {
        int hb = bid - 80;          // 0..127 = h*16 + qt
        int h = hb >> 4, qt = hb & 15;
        int cc = tid >> 4, n = tid & 15;
        const float* src = bias + ((size_t)(h*256 + qt*16 + cc))*256 + n*16;
        float* dst = bt + ((size_t)(hb*16 + n))*256 + cc*16;
        #pragma unroll
        for (int q = 0; q < 4; ++q)
            *(f32x4*)(dst + q*4) = *(const f32x4*)(src + q*4);
    }
}

// ---------- proj K-loop, 2 col-tiles/wave (depth-1 weight prefetch) ----------
// As: 64x256 bf16 tile, row stride 512 B, byte-col XOR ((row&31)<<4).
template<int SWAP>
__device__ __forceinline__ void proj_mfma_loop2(
    const unsigned short* As, const unsigned short* Wt,
    int col0, int c, int g, f32x4 acc[4][2])
{
    short8 pb[2];
    #pragma unroll
    for (int n = 0; n < 2; ++n)
        pb[n] = *(const short8*)(Wt + (size_t)(col0 + n*16 + c) * 256 + g*8);

    #pragma unroll
    for (int step = 0; step < 8; ++step) {
        short8 b[2];
        #pragma unroll
        for (int n = 0; n < 2; ++n) b[n] = pb[n];
        if (step < 7) {
            int koff = (step + 1) * 32 + g * 8;
            #pragma unroll
            for (int n = 0; n < 2; ++n)
                pb[n] = *(const short8*)(Wt + (size_t)(col0 + n*16 + c) * 256 + koff);
        }
        short8 a[4];
        #pragma unroll
        for (int m = 0; m < 4; ++m) {
            int row = m * 16 + c;
            int off = row * 512 + ((step * 64 + g * 16) ^ ((row & 31) << 4));
            a[m] = *(const short8*)((const char*)As + off);
        }
        #pragma unroll
        for (int m = 0; m < 4; ++m)
            #pragma unroll
            for (int n = 0; n < 2; ++n) {
                if (SWAP)
                    acc[m][n] = __builtin_amdgcn_mfma_f32_16x16x32_bf16(b[n], a[m], acc[m][n], 0, 0, 0);
                else
                    acc[m][n] = __builtin_amdgcn_mfma_f32_16x16x32_bf16(a[m], b[n], acc[m][n], 0, 0, 0);
            }
    }
}

// ---------- kernel 1: projections, 3-phase pipeline with async loads ----------
// Phase t: {pack prev loads -> ds_write LDS[t&1]; issue next loads;
//           lgkm-only barrier (loads stay in flight); compute}.
__global__ __launch_bounds__(512, 2) void proj_kernel(
    const float* __restrict__ qx, const float* __restrict__ kx, const float* __restrict__ vx,
    const float* __restrict__ bg, const unsigned short* __restrict__ wt,
    unsigned short* __restrict__ Qa, unsigned short* __restrict__ Ka,
    unsigned short* __restrict__ Va, unsigned short* __restrict__ G)
{
    __shared__ __align__(16) unsigned short As[2][64 * 256];   // 2 x 32 KB

    int rb = blockIdx.x;
    int row0 = rb * 64;
    int tid = threadIdx.x;
    int w = tid >> 6, lane = tid & 63;
    int c = lane & 15, g = lane >> 4;
    int col0 = w * 32;
    int l32 = tid & 31, rg = tid >> 5;      // staging coords
    int r_ = row0 >> 8;
    int s0b = row0 & 255;
    int h_ = col0 >> 5;                     // one head per wave

    f32x4 ld[8];                            // raw f32 tile in flight (32 VGPR)

    // prologue: issue qx loads
    #pragma unroll
    for (int j = 0; j < 4; ++j) {
        const float* src = qx + (size_t)(row0 + j*16 + rg) * 256 + l32 * 8;
        ld[2*j]   = *(const f32x4*)src;
        ld[2*j+1] = *(const f32x4*)(src + 4);
    }

    // ================= phase 0: Q + G from qx =================
    #pragma unroll
    for (int j = 0; j < 4; ++j) {
        int row = j*16 + rg;
        u32x4 pkv;
        pkv[0] = pack2(ld[2*j][0],   ld[2*j][1]);   pkv[1] = pack2(ld[2*j][2],   ld[2*j][3]);
        pkv[2] = pack2(ld[2*j+1][0], ld[2*j+1][1]); pkv[3] = pack2(ld[2*j+1][2], ld[2*j+1][3]);
        int off = row * 512 + ((l32 * 16) ^ ((row & 31) << 4));
        *(u32x4*)((char*)&As[0][0] + off) = pkv;
    }
    // issue kx loads (stay in flight across barrier; first use = phase-1 pack)
    #pragma unroll
    for (int j = 0; j < 4; ++j) {
        const float* src = kx + (size_t)(row0 + j*16 + rg) * 256 + l32 * 8;
        ld[2*j]   = *(const f32x4*)src;
        ld[2*j+1] = *(const f32x4*)(src + 4);
    }
    barrier_lgkm_only();
    {
        f32x4 acc[4][2];
        #pragma unroll
        for (int m = 0; m < 4; ++m)
            #pragma unroll
            for (int n = 0; n < 2; ++n) acc[m][n] = 0.0f;
        proj_mfma_loop2<1>(&As[0][0], wt, col0, c, g, acc);
        #pragma unroll
        for (int m = 0; m < 4; ++m) {
            int s_ = s0b + m * 16 + c;
            u16x8 st;
            #pragma unroll
            for (int i = 0; i < 4; ++i) {
                st[i]     = (unsigned short)bfbits(acc[m][0][i]);
                st[i + 4] = (unsigned short)bfbits(acc[m][1][i]);
            }
            *(u16x8*)(Qa + ((size_t)((r_*8 + h_)*256 + s_)) * 32 + 8*g) = st;
        }
        // G
        #pragma unroll
        for (int m = 0; m < 4; ++m)
            #pragma unroll
            for (int n = 0; n < 2; ++n) acc[m][n] = 0.0f;
        proj_mfma_loop2<1>(&As[0][0], wt + 3*65536, col0, c, g, acc);
        f32x4 bg0 = *(const f32x4*)(bg + col0 + 4*g);
        f32x4 bg1 = *(const f32x4*)(bg + col0 + 16 + 4*g);
        #pragma unroll
        for (int m = 0; m < 4; ++m) {
            int rq = row0 + m * 16 + c;
            u16x8 st;
            #pragma unroll
            for (int i = 0; i < 4; ++i) {
                float sa = 1.0f / (1.0f + __expf(-(acc[m][0][i] + bg0[i])));
                float sb = 1.0f / (1.0f + __expf(-(acc[m][1][i] + bg1[i])));
                st[i]     = (unsigned short)bfbits(sa);
                st[i + 4] = (unsigned short)bfbits(sb);
            }
            *(u16x8*)(G + (size_t)rq * 256 + col0 + 8*g) = st;
        }
    }

    // ================= phase 1: K from kx =================
    #pragma unroll
    for (int j = 0; j < 4; ++j) {
        int row = j*16 + rg;
        u32x4 pkv;
        pkv[0] = pack2(ld[2*j][0],   ld[2*j][1]);   pkv[1] = pack2(ld[2*j][2],   ld[2*j][3]);
        pkv[2] = pack2(ld[2*j+1][0], ld[2*j+1][1]); pkv[3] = pack2(ld[2*j+1][2], ld[2*j+1][3]);
        int off = row * 512 + ((l32 * 16) ^ ((row & 31) << 4));
        *(u32x4*)((char*)&As[1][0] + off) = pkv;
    }
    // issue vx loads
    #pragma unroll
    for (int j = 0; j < 4; ++j) {
        const float* src = vx + (size_t)(row0 + j*16 + rg) * 256 + l32 * 8;
        ld[2*j]   = *(const f32x4*)src;
        ld[2*j+1] = *(const f32x4*)(src + 4);
    }
    barrier_lgkm_only();
    {
        f32x4 acc[4][2];
        #pragma unroll
        for (int m = 0; m < 4; ++m)
            #pragma unroll
            for (int n = 0; n < 2; ++n) acc[m][n] = 0.0f;
        proj_mfma_loop2<1>(&As[1][0], wt + 65536, col0, c, g, acc);
        #pragma unroll
        for (int m = 0; m < 4; ++m) {
            int s_ = s0b + m * 16 + c;
            u16x8 st;
            #pragma unroll
            for (int i = 0; i < 4; ++i) {
                st[i]     = (unsigned short)bfbits(acc[m][0][i]);
                st[i + 4] = (unsigned short)bfbits(acc[m][1][i]);
            }
            *(u16x8*)(Ka + ((size_t)((r_*8 + h_)*256 + s_)) * 32 + 8*g) = st;
        }
    }

    // ================= phase 2: V from vx =================
    // WAR-safe: every wave finished phase-0's LDS[0] reads before phase-1's barrier.
    #pragma unroll
    for (int j = 0; j < 4; ++j) {
        int row = j*16 + rg;
        u32x4 pkv;
        pkv[0] = pack2(ld[2*j][0],   ld[2*j][1]);   pkv[1] = pack2(ld[2*j][2],   ld[2*j][3]);
        pkv[2] = pack2(ld[2*j+1][0], ld[2*j+1][1]); pkv[3] = pack2(ld[2*j+1][2], ld[2*j+1][3]);
        int off = row * 512 + ((l32 * 16) ^ ((row & 31) << 4));
        *(u32x4*)((char*)&As[0][0] + off) = pkv;
    }
    barrier_lgkm_only();
    {
        f32x4 acc[4][2];
        #pragma unroll
        for (int m = 0; m < 4; ++m)
            #pragma unroll
            for (int n = 0; n < 2; ++n) acc[m][n] = 0.0f;
        proj_mfma_loop2<0>(&As[0][0], wt + 2*65536, col0, c, g, acc);
        #pragma unroll
        for (int n = 0; n < 2; ++n) {
            int d_ = n*16 + c;
            size_t rowbase = ((size_t)((r_*8 + h_)*32 + d_)) * 256;
            #pragma unroll
            for (int p = 0; p < 2; ++p) {    // m-pairs (0,1),(2,3) -> tau slots
                u16x8 st;
                #pragma unroll
                for (int i = 0; i < 4; ++i) {
                    st[i]     = (unsigned short)bfbits(acc[2*p][n][i]);
                    st[i + 4] = (unsigned short)bfbits(acc[2*p+1][n][i]);
                }
                *(u16x8*)(Va + rowbase + s0b + 32*p + 8*g) = st;
            }
        }
    }
}

// ---------- kernel 2: attention, one block per (r,h), K/V in LDS ----------
__global__ __launch_bounds__(512) void attn_kernel(
    const unsigned short* __restrict__ Qa, const unsigned short* __restrict__ Ka,
    const unsigned short* __restrict__ Va, const unsigned short* __restrict__ G,
    const float* __restrict__ bt, unsigned short* __restrict__ og)
{
    __shared__ __align__(16) unsigned short Ks[256 * 40];  // [s][d'] pad 40
    __shared__ __align__(16) unsigned short Vs[32 * 264];  // [d][s'=slot] pad 264

    int rh = blockIdx.x;            // 0..1023
    int r = rh >> 3, h = rh & 7;
    int tid = threadIdx.x;          // 512 threads
    int w = tid >> 6, lane = tid & 63;
    int c = lane & 15, g = lane >> 4;
    size_t base = (size_t)rh * 8192;

    #pragma unroll
    for (int j = 0; j < 2; ++j) {
        int idx8 = (tid + j*512) * 8;
        int s_ = idx8 >> 5, d_ = idx8 & 31;
        short8 v = *(const short8*)(Ka + base + idx8);
        *(short8*)(&Ks[s_*40 + d_]) = v;
    }
    #pragma unroll
    for (int j = 0; j < 2; ++j) {
        int idx8 = (tid + j*512) * 8;
        int d_ = idx8 >> 8, s0 = idx8 & 255;
        short8 v = *(const short8*)(Va + base + idx8);
        *(short8*)(&Vs[d_*264 + s0]) = v;
    }
    __syncthreads();

    const float* bth = bt + (size_t)h * 65536;
    const float nrmv = 0.17677669529663687f;

    #pragma unroll 1
    for (int qq = 0; qq < 2; ++qq) {
        int qt = w*2 + qq;                 // 0..15
        int qrow = qt * 16;
        short8 qf = *(const short8*)(Qa + base + (size_t)(qrow + c)*32 + g*8);
        const float* btt = bth + (size_t)qt*4096 + (c*4 + g)*4;

        f32x4 o0 = 0.0f, o1 = 0.0f;
        float sum = 0.f;
        #pragma unroll
        for (int t = 0; t < 8; ++t) {
            int n0 = 2*t, n1 = 2*t + 1;
            short8 kf0 = *(const short8*)(&Ks[(n0*16 + c)*40 + g*8]);
            short8 kf1 = *(const short8*)(&Ks[(n1*16 + c)*40 + g*8]);
            f32x4 bv0 = *(const f32x4*)(btt + n0*256);
            f32x4 bv1 = *(const f32x4*)(btt + n1*256);
            f32x4 z = 0.0f;
            f32x4 s0 = __builtin_amdgcn_mfma_f32_16x16x32_bf16(kf0, qf, z, 0, 0, 0);
            f32x4 s1 = __builtin_amdgcn_mfma_f32_16x16x32_bf16(kf1, qf, z, 0, 0, 0);
            float e0 = __expf(fmaf(s0[0], nrmv, bv0[0]));
            float e1 = __expf(fmaf(s0[1], nrmv, bv0[1]));
            float e2 = __expf(fmaf(s0[2], nrmv, bv0[2]));
            float e3 = __expf(fmaf(s0[3], nrmv, bv0[3]));
            float e4 = __expf(fmaf(s1[0], nrmv, bv1[0]));
            float e5 = __expf(fmaf(s1[1], nrmv, bv1[1]));
            float e6 = __expf(fmaf(s1[2], nrmv, bv1[2]));
            float e7 = __expf(fmaf(s1[3], nrmv, bv1[3]));
            sum += ((e0+e1)+(e2+e3)) + ((e4+e5)+(e6+e7));
            u32x4 aw;
            aw[0] = pack2(e0, e1); aw[1] = pack2(e2, e3);
            aw[2] = pack2(e4, e5); aw[3] = pack2(e6, e7);
            short8 pfrag = __builtin_bit_cast(short8, aw);
            short8 va0 = *(const short8*)(&Vs[(c)*264      + t*32 + g*8]);
            short8 va1 = *(const short8*)(&Vs[(16 + c)*264 + t*32 + g*8]);
            o0 = __builtin_amdgcn_mfma_f32_16x16x32_bf16(va0, pfrag, o0, 0, 0, 0);
            o1 = __builtin_amdgcn_mfma_f32_16x16x32_bf16(va1, pfrag, o1, 0, 0, 0);
        }
        sum += __shfl_xor(sum, 16);
        sum += __shfl_xor(sum, 32);
        float inv = 1.0f / sum;

        size_t orow = ((size_t)(r*256 + qrow + c)) * 256 + h*32 + 8*g;
        u16x8 gv = *(const u16x8*)(G + orow);
        u16x8 st;
        #pragma unroll
        for (int i = 0; i < 4; ++i) {
            st[i]     = (unsigned short)bfbits(o0[i] * inv * bf2f(gv[i]));
            st[i + 4] = (unsigned short)bfbits(o1[i] * inv * bf2f(gv[i + 4]));
        }
        *(u16x8*)(og + orow) = st;
    }
}

// ---------- oproj K-loop (As: 64x256 swizzled tile, swapped) ----------
__device__ __forceinline__ void proj_mfma_loop_swap(
    const unsigned short* As, const unsigned short* Wt,
    int col0, int c, int g, f32x4 acc[4][4])
{
    short8 pb[4];
    #pragma unroll
    for (int n = 0; n < 4; ++n)
        pb[n] = *(const short8*)(Wt + (size_t)(col0 + n*16 + c) * 256 + g*8);

    #pragma unroll
    for (int step = 0; step < 8; ++step) {
        short8 b[4];
        #pragma unroll
        for (int n = 0; n < 4; ++n) b[n] = pb[n];
        if (step < 7) {
            int koff = (step + 1) * 32 + g * 8;
            #pragma unroll
            for (int n = 0; n < 4; ++n)
                pb[n] = *(const short8*)(Wt + (size_t)(col0 + n*16 + c) * 256 + koff);
        }
        short8 a[4];
        #pragma unroll
        for (int m = 0; m < 4; ++m) {
            int row = m * 16 + c;
            int off = row * 512 + ((step * 64 + g * 16) ^ ((row & 31) << 4));
            a[m] = *(const short8*)((const char*)As + off);
        }
        #pragma unroll
        for (int m = 0; m < 4; ++m)
            #pragma unroll
            for (int n = 0; n < 4; ++n)
                acc[m][n] = __builtin_amdgcn_mfma_f32_16x16x32_bf16(b[n], a[m], acc[m][n], 0, 0, 0);
    }
}

// ---------- kernel 3: output projection (LDS-staged og, swapped MFMA) ----------
__global__ __launch_bounds__(256) void oproj_kernel(
    const unsigned short* __restrict__ og, const unsigned short* __restrict__ wt_o,
    const float* __restrict__ bo, float* __restrict__ out)
{
    __shared__ __align__(16) unsigned short As[64 * 256];

    int row0 = blockIdx.x * 64;
    int tid = threadIdx.x;
    int lane = tid & 63;
    int c = lane & 15, g = lane >> 4;
    int col0 = (tid >> 6) * 64;

    #pragma unroll
    for (int j = 0; j < 8; ++j) {
        int idx = tid * 8 + j * 2048;
        int row = idx >> 8;
        int colB = (idx & 255) * 2;
        short8 v = *(const short8*)(og + (size_t)(row0 + row) * 256 + (idx & 255));
        int off = row * 512 + (colB ^ ((row & 31) << 4));
        *(short8*)((char*)As + off) = v;
    }
    __syncthreads();

    f32x4 acc[4][4];
    #pragma unroll
    for (int m = 0; m < 4; ++m)
        #pragma unroll
        for (int n = 0; n < 4; ++n)
            acc[m][n] = 0.0f;

    proj_mfma_loop_swap(As, wt_o, col0, c, g, acc);

    #pragma unroll
    for (int n = 0; n < 4; ++n) {
        int colb = col0 + n * 16 + 4 * g;
        f32x4 bov = *(const f32x4*)(bo + colb);
        #pragma unroll
        for (int m = 0; m < 4; ++m) {
            int row = row0 + m * 16 + c;
            f32x4 st = acc[m][n] + bov;
            *(f32x4*)(out + (size_t)row * 256 + colb) = st;
        }
    }
}

extern "C" void kernel_launch(void* const* d_in, const int* in_sizes, int n_in,
                              void* d_out, int out_size, void* d_ws, size_t ws_size,
                              hipStream_t stream) {
    const float* qx   = (const float*)d_in[0];
    const float* kx   = (const float*)d_in[1];
    const float* vx   = (const float*)d_in[2];
    const float* bias = (const float*)d_in[3];
    const float* Wq   = (const float*)d_in[4];
    const float* Wk   = (const float*)d_in[5];
    const float* Wv   = (const float*)d_in[6];
    const float* Wo   = (const float*)d_in[7];
    const float* bo   = (const float*)d_in[8];
    const float* Wg   = (const float*)d_in[9];
    const float* bg   = (const float*)d_in[10];

    uint8_t* ws = (uint8_t*)d_ws;
    unsigned short* wt = (unsigned short*)ws;                         // 640 KB
    unsigned short* Qa = (unsigned short*)(ws + (1u<<20));
    unsigned short* Ka = (unsigned short*)(ws + (1u<<20) + 1u*(1u<<24));
    unsigned short* Va = (unsigned short*)(ws + (1u<<20) + 2u*(1u<<24));
    unsigned short* G  = (unsigned short*)(ws + (1u<<20) + 3u*(1u<<24));
    unsigned short* og = (unsigned short*)(ws + (1u<<20) + 4u*(1u<<24));
    float*          bt = (float*)        (ws + (1u<<20) + 5u*(1u<<24)); // 2 MB

    hipLaunchKernelGGL(prep_kernel, dim3(208), dim3(256), 0, stream,
                       Wq, Wk, Wv, Wg, Wo, wt, bias, bt);
    hipLaunchKernelGGL(proj_kernel, dim3(512), dim3(512), 0, stream,
                       qx, kx, vx, bg, wt, Qa, Ka, Va, G);
    hipLaunchKernelGGL(attn_kernel, dim3(1024), dim3(512), 0, stream,
                       Qa, Ka, Va, G, bt, og);
    hipLaunchKernelGGL(oproj_kernel, dim3(512), dim3(256), 0, stream,
                       og, wt + 4*65536, bo, (float*)d_out);
}

// Round 21
// 107.040 us; speedup vs baseline: 1.3706x; 1.1203x over previous
//
#include <hip/hip_runtime.h>
#include <hip/hip_bf16.h>
#include <cstdint>
#include <cstddef>

typedef __attribute__((ext_vector_type(8))) short short8;
typedef __attribute__((ext_vector_type(4))) short s16x4;
typedef __attribute__((ext_vector_type(4))) unsigned short u16x4;
typedef __attribute__((ext_vector_type(8))) unsigned short u16x8;
typedef __attribute__((ext_vector_type(4))) float f32x4;
typedef __attribute__((ext_vector_type(4))) unsigned int u32x4;

__device__ __forceinline__ short bfbits(float f) {
    __bf16 h = (__bf16)f;
    return __builtin_bit_cast(short, h);
}
__device__ __forceinline__ float bf2f(unsigned short b) {
    union { uint32_t u; float f; } v; v.u = ((uint32_t)b) << 16;
    return v.f;
}
__device__ __forceinline__ unsigned int pack2(float x, float y) {
    return (unsigned int)(unsigned short)bfbits(x) |
           ((unsigned int)(unsigned short)bfbits(y) << 16);
}

// lgkmcnt-only barrier: makes ds_writes visible without draining vmcnt,
// so global loads issued before it stay in flight across the barrier (T4).
__device__ __forceinline__ void barrier_lgkm_only() {
    asm volatile("s_waitcnt lgkmcnt(0)" ::: "memory");
    __builtin_amdgcn_s_barrier();
}

// ---------- kernel 0: weight transpose + bias tiling (merged prep) ----------
__global__ __launch_bounds__(256) void prep_kernel(
    const float* __restrict__ Wq, const float* __restrict__ Wk,
    const float* __restrict__ Wv, const float* __restrict__ Wg,
    const float* __restrict__ Wo, unsigned short* __restrict__ wt,
    const float* __restrict__ bias, float* __restrict__ bt)
{
    int bid = blockIdx.x;
    int tid = threadIdx.x;
    if (bid < 80) {
        int mat  = bid >> 4;
        int tile = bid & 15;
        int k0 = (tile >> 2) * 64, n0 = (tile & 3) * 64;
        const float* W = (mat==0)?Wq:(mat==1)?Wk:(mat==2)?Wv:(mat==3)?Wg:Wo;
        __shared__ unsigned short T[64][72];   // T[n][k]
        int tx = tid & 15, ty = tid >> 4;
        #pragma unroll
        for (int j = 0; j < 4; ++j) {
            int kr = ty + j*16;
            f32x4 v = *(const f32x4*)(W + (size_t)(k0+kr)*256 + n0 + tx*4);
            #pragma unroll
            for (int e = 0; e < 4; ++e) T[tx*4+e][kr] = (unsigned short)bfbits(v[e]);
        }
        __syncthreads();
        #pragma unroll
        for (int j = 0; j < 4; ++j) {
            int nr = ty + j*16;
            int kk = k0 + tx*4;
            int dstk = kk;
            if (mat == 4) {
                // sigma within each 32-block of k: 4a+e -> 8a+e (a<4), 16+4g+e -> 8g+4+e
                int a = (kk >> 2) & 7;
                int hb = kk & ~31;
                dstk = hb + ((a < 4) ? 8*a : 8*(a-4) + 4);
            }
            u16x4 st;
            #pragma unroll
            for (int e = 0; e < 4; ++e) st[e] = T[nr][tx*4+e];
            *(u16x4*)(wt + ((size_t)mat*256 + n0+nr)*256 + dstk) = st;
        }
    } else {
        int hb = bid - 80;          // 0..127 = h*16 + qt
        int h = hb >> 4, qt = hb & 15;
        int cc = tid >> 4, n = tid & 15;
        const float* src = bias + ((size_t)(h*256 + qt*16 + cc))*256 + n*16;
        float* dst = bt + ((size_t)(hb*16 + n))*256 + cc*16;
        #pragma unroll
        for (int q = 0; q < 4; ++q)
            *(f32x4*)(dst + q*4) = *(const f32x4*)(src + q*4);
    }
}

// ---------- proj K-loop, 2 col-tiles/wave (depth-1 weight prefetch) ----------
// As: 64x256 bf16 tile, row stride 512 B, byte-col XOR ((row&31)<<4).
template<int SWAP>
__device__ __forceinline__ void proj_mfma_loop2(
    const unsigned short* As, const unsigned short* Wt,
    int col0, int c, int g, f32x4 acc[4][2])
{
    short8 pb[2];
    #pragma unroll
    for (int n = 0; n < 2; ++n)
        pb[n] = *(const short8*)(Wt + (size_t)(col0 + n*16 + c) * 256 + g*8);

    #pragma unroll
    for (int step = 0; step < 8; ++step) {
        short8 b[2];
        #pragma unroll
        for (int n = 0; n < 2; ++n) b[n] = pb[n];
        if (step < 7) {
            int koff = (step + 1) * 32 + g * 8;
            #pragma unroll
            for (int n = 0; n < 2; ++n)
                pb[n] = *(const short8*)(Wt + (size_t)(col0 + n*16 + c) * 256 + koff);
        }
        short8 a[4];
        #pragma unroll
        for (int m = 0; m < 4; ++m) {
            int row = m * 16 + c;
            int off = row * 512 + ((step * 64 + g * 16) ^ ((row & 31) << 4));
            a[m] = *(const short8*)((const char*)As + off);
        }
        #pragma unroll
        for (int m = 0; m < 4; ++m)
            #pragma unroll
            for (int n = 0; n < 2; ++n) {
                if (SWAP)
                    acc[m][n] = __builtin_amdgcn_mfma_f32_16x16x32_bf16(b[n], a[m], acc[m][n], 0, 0, 0);
                else
                    acc[m][n] = __builtin_amdgcn_mfma_f32_16x16x32_bf16(a[m], b[n], acc[m][n], 0, 0, 0);
            }
    }
}

// ---------- kernel 1: projections, 3-phase pipeline with async loads ----------
// Phase t: {pack prev loads -> ds_write LDS[t&1]; issue next loads;
//           lgkm-only barrier (loads stay in flight); compute}.
__global__ __launch_bounds__(512, 2) void proj_kernel(
    const float* __restrict__ qx, const float* __restrict__ kx, const float* __restrict__ vx,
    const float* __restrict__ bg, const unsigned short* __restrict__ wt,
    unsigned short* __restrict__ Qa, unsigned short* __restrict__ Ka,
    unsigned short* __restrict__ Va, unsigned short* __restrict__ G)
{
    __shared__ __align__(16) unsigned short As[2][64 * 256];   // 2 x 32 KB

    int rb = blockIdx.x;
    int row0 = rb * 64;
    int tid = threadIdx.x;
    int w = tid >> 6, lane = tid & 63;
    int c = lane & 15, g = lane >> 4;
    int col0 = w * 32;
    int l32 = tid & 31, rg = tid >> 5;      // staging coords
    int r_ = row0 >> 8;
    int s0b = row0 & 255;
    int h_ = col0 >> 5;                     // one head per wave

    f32x4 ld[8];                            // raw f32 tile in flight (32 VGPR)

    // prologue: issue qx loads
    #pragma unroll
    for (int j = 0; j < 4; ++j) {
        const float* src = qx + (size_t)(row0 + j*16 + rg) * 256 + l32 * 8;
        ld[2*j]   = *(const f32x4*)src;
        ld[2*j+1] = *(const f32x4*)(src + 4);
    }

    // ================= phase 0: Q + G from qx =================
    #pragma unroll
    for (int j = 0; j < 4; ++j) {
        int row = j*16 + rg;
        u32x4 pkv;
        pkv[0] = pack2(ld[2*j][0],   ld[2*j][1]);   pkv[1] = pack2(ld[2*j][2],   ld[2*j][3]);
        pkv[2] = pack2(ld[2*j+1][0], ld[2*j+1][1]); pkv[3] = pack2(ld[2*j+1][2], ld[2*j+1][3]);
        int off = row * 512 + ((l32 * 16) ^ ((row & 31) << 4));
        *(u32x4*)((char*)&As[0][0] + off) = pkv;
    }
    // issue kx loads (stay in flight across barrier; first use = phase-1 pack)
    #pragma unroll
    for (int j = 0; j < 4; ++j) {
        const float* src = kx + (size_t)(row0 + j*16 + rg) * 256 + l32 * 8;
        ld[2*j]   = *(const f32x4*)src;
        ld[2*j+1] = *(const f32x4*)(src + 4);
    }
    barrier_lgkm_only();
    {
        f32x4 acc[4][2];
        #pragma unroll
        for (int m = 0; m < 4; ++m)
            #pragma unroll
            for (int n = 0; n < 2; ++n) acc[m][n] = 0.0f;
        proj_mfma_loop2<1>(&As[0][0], wt, col0, c, g, acc);
        #pragma unroll
        for (int m = 0; m < 4; ++m) {
            int s_ = s0b + m * 16 + c;
            u16x8 st;
            #pragma unroll
            for (int i = 0; i < 4; ++i) {
                st[i]     = (unsigned short)bfbits(acc[m][0][i]);
                st[i + 4] = (unsigned short)bfbits(acc[m][1][i]);
            }
            *(u16x8*)(Qa + ((size_t)((r_*8 + h_)*256 + s_)) * 32 + 8*g) = st;
        }
        // G
        #pragma unroll
        for (int m = 0; m < 4; ++m)
            #pragma unroll
            for (int n = 0; n < 2; ++n) acc[m][n] = 0.0f;
        proj_mfma_loop2<1>(&As[0][0], wt + 3*65536, col0, c, g, acc);
        f32x4 bg0 = *(const f32x4*)(bg + col0 + 4*g);
        f32x4 bg1 = *(const f32x4*)(bg + col0 + 16 + 4*g);
        #pragma unroll
        for (int m = 0; m < 4; ++m) {
            int rq = row0 + m * 16 + c;
            u16x8 st;
            #pragma unroll
            for (int i = 0; i < 4; ++i) {
                float sa = 1.0f / (1.0f + __expf(-(acc[m][0][i] + bg0[i])));
                float sb = 1.0f / (1.0f + __expf(-(acc[m][1][i] + bg1[i])));
                st[i]     = (unsigned short)bfbits(sa);
                st[i + 4] = (unsigned short)bfbits(sb);
            }
            *(u16x8*)(G + (size_t)rq * 256 + col0 + 8*g) = st;
        }
    }

    // ================= phase 1: K from kx =================
    #pragma unroll
    for (int j = 0; j < 4; ++j) {
        int row = j*16 + rg;
        u32x4 pkv;
        pkv[0] = pack2(ld[2*j][0],   ld[2*j][1]);   pkv[1] = pack2(ld[2*j][2],   ld[2*j][3]);
        pkv[2] = pack2(ld[2*j+1][0], ld[2*j+1][1]); pkv[3] = pack2(ld[2*j+1][2], ld[2*j+1][3]);
        int off = row * 512 + ((l32 * 16) ^ ((row & 31) << 4));
        *(u32x4*)((char*)&As[1][0] + off) = pkv;
    }
    // issue vx loads
    #pragma unroll
    for (int j = 0; j < 4; ++j) {
        const float* src = vx + (size_t)(row0 + j*16 + rg) * 256 + l32 * 8;
        ld[2*j]   = *(const f32x4*)src;
        ld[2*j+1] = *(const f32x4*)(src + 4);
    }
    barrier_lgkm_only();
    {
        f32x4 acc[4][2];
        #pragma unroll
        for (int m = 0; m < 4; ++m)
            #pragma unroll
            for (int n = 0; n < 2; ++n) acc[m][n] = 0.0f;
        proj_mfma_loop2<1>(&As[1][0], wt + 65536, col0, c, g, acc);
        #pragma unroll
        for (int m = 0; m < 4; ++m) {
            int s_ = s0b + m * 16 + c;
            u16x8 st;
            #pragma unroll
            for (int i = 0; i < 4; ++i) {
                st[i]     = (unsigned short)bfbits(acc[m][0][i]);
                st[i + 4] = (unsigned short)bfbits(acc[m][1][i]);
            }
            *(u16x8*)(Ka + ((size_t)((r_*8 + h_)*256 + s_)) * 32 + 8*g) = st;
        }
    }

    // ================= phase 2: V from vx =================
    // WAR-safe: every wave finished phase-0's LDS[0] reads before phase-1's barrier.
    #pragma unroll
    for (int j = 0; j < 4; ++j) {
        int row = j*16 + rg;
        u32x4 pkv;
        pkv[0] = pack2(ld[2*j][0],   ld[2*j][1]);   pkv[1] = pack2(ld[2*j][2],   ld[2*j][3]);
        pkv[2] = pack2(ld[2*j+1][0], ld[2*j+1][1]); pkv[3] = pack2(ld[2*j+1][2], ld[2*j+1][3]);
        int off = row * 512 + ((l32 * 16) ^ ((row & 31) << 4));
        *(u32x4*)((char*)&As[0][0] + off) = pkv;
    }
    barrier_lgkm_only();
    {
        f32x4 acc[4][2];
        #pragma unroll
        for (int m = 0; m < 4; ++m)
            #pragma unroll
            for (int n = 0; n < 2; ++n) acc[m][n] = 0.0f;
        proj_mfma_loop2<0>(&As[0][0], wt + 2*65536, col0, c, g, acc);
        #pragma unroll
        for (int n = 0; n < 2; ++n) {
            int d_ = n*16 + c;
            size_t rowbase = ((size_t)((r_*8 + h_)*32 + d_)) * 256;
            #pragma unroll
            for (int p = 0; p < 2; ++p) {    // m-pairs (0,1),(2,3) -> tau slots
                u16x8 st;
                #pragma unroll
                for (int i = 0; i < 4; ++i) {
                    st[i]     = (unsigned short)bfbits(acc[2*p][n][i]);
                    st[i + 4] = (unsigned short)bfbits(acc[2*p+1][n][i]);
                }
                *(u16x8*)(Va + rowbase + s0b + 32*p + 8*g) = st;
            }
        }
    }
}

// ---------- kernel 2: attention, one block per (r,h), K/V in LDS ----------
// R21: qq loop unrolled (ILP across q-tiles) + s_setprio around MFMA core (T5).
__global__ __launch_bounds__(512) void attn_kernel(
    const unsigned short* __restrict__ Qa, const unsigned short* __restrict__ Ka,
    const unsigned short* __restrict__ Va, const unsigned short* __restrict__ G,
    const float* __restrict__ bt, unsigned short* __restrict__ og)
{
    __shared__ __align__(16) unsigned short Ks[256 * 40];  // [s][d'] pad 40
    __shared__ __align__(16) unsigned short Vs[32 * 264];  // [d][s'=slot] pad 264

    int rh = blockIdx.x;            // 0..1023
    int r = rh >> 3, h = rh & 7;
    int tid = threadIdx.x;          // 512 threads
    int w = tid >> 6, lane = tid & 63;
    int c = lane & 15, g = lane >> 4;
    size_t base = (size_t)rh * 8192;

    #pragma unroll
    for (int j = 0; j < 2; ++j) {
        int idx8 = (tid + j*512) * 8;
        int s_ = idx8 >> 5, d_ = idx8 & 31;
        short8 v = *(const short8*)(Ka + base + idx8);
        *(short8*)(&Ks[s_*40 + d_]) = v;
    }
    #pragma unroll
    for (int j = 0; j < 2; ++j) {
        int idx8 = (tid + j*512) * 8;
        int d_ = idx8 >> 8, s0 = idx8 & 255;
        short8 v = *(const short8*)(Va + base + idx8);
        *(short8*)(&Vs[d_*264 + s0]) = v;
    }
    __syncthreads();

    const float* bth = bt + (size_t)h * 65536;
    const float nrmv = 0.17677669529663687f;

    #pragma unroll
    for (int qq = 0; qq < 2; ++qq) {
        int qt = w*2 + qq;                 // 0..15
        int qrow = qt * 16;
        short8 qf = *(const short8*)(Qa + base + (size_t)(qrow + c)*32 + g*8);
        const float* btt = bth + (size_t)qt*4096 + (c*4 + g)*4;

        f32x4 o0 = 0.0f, o1 = 0.0f;
        float sum = 0.f;
        __builtin_amdgcn_s_setprio(1);
        #pragma unroll
        for (int t = 0; t < 8; ++t) {
            int n0 = 2*t, n1 = 2*t + 1;
            short8 kf0 = *(const short8*)(&Ks[(n0*16 + c)*40 + g*8]);
            short8 kf1 = *(const short8*)(&Ks[(n1*16 + c)*40 + g*8]);
            f32x4 bv0 = *(const f32x4*)(btt + n0*256);
            f32x4 bv1 = *(const f32x4*)(btt + n1*256);
            f32x4 z = 0.0f;
            f32x4 s0 = __builtin_amdgcn_mfma_f32_16x16x32_bf16(kf0, qf, z, 0, 0, 0);
            f32x4 s1 = __builtin_amdgcn_mfma_f32_16x16x32_bf16(kf1, qf, z, 0, 0, 0);
            float e0 = __expf(fmaf(s0[0], nrmv, bv0[0]));
            float e1 = __expf(fmaf(s0[1], nrmv, bv0[1]));
            float e2 = __expf(fmaf(s0[2], nrmv, bv0[2]));
            float e3 = __expf(fmaf(s0[3], nrmv, bv0[3]));
            float e4 = __expf(fmaf(s1[0], nrmv, bv1[0]));
            float e5 = __expf(fmaf(s1[1], nrmv, bv1[1]));
            float e6 = __expf(fmaf(s1[2], nrmv, bv1[2]));
            float e7 = __expf(fmaf(s1[3], nrmv, bv1[3]));
            sum += ((e0+e1)+(e2+e3)) + ((e4+e5)+(e6+e7));
            u32x4 aw;
            aw[0] = pack2(e0, e1); aw[1] = pack2(e2, e3);
            aw[2] = pack2(e4, e5); aw[3] = pack2(e6, e7);
            short8 pfrag = __builtin_bit_cast(short8, aw);
            short8 va0 = *(const short8*)(&Vs[(c)*264      + t*32 + g*8]);
            short8 va1 = *(const short8*)(&Vs[(16 + c)*264 + t*32 + g*8]);
            o0 = __builtin_amdgcn_mfma_f32_16x16x32_bf16(va0, pfrag, o0, 0, 0, 0);
            o1 = __builtin_amdgcn_mfma_f32_16x16x32_bf16(va1, pfrag, o1, 0, 0, 0);
        }
        __builtin_amdgcn_s_setprio(0);
        sum += __shfl_xor(sum, 16);
        sum += __shfl_xor(sum, 32);
        float inv = 1.0f / sum;

        size_t orow = ((size_t)(r*256 + qrow + c)) * 256 + h*32 + 8*g;
        u16x8 gv = *(const u16x8*)(G + orow);
        u16x8 st;
        #pragma unroll
        for (int i = 0; i < 4; ++i) {
            st[i]     = (unsigned short)bfbits(o0[i] * inv * bf2f(gv[i]));
            st[i + 4] = (unsigned short)bfbits(o1[i] * inv * bf2f(gv[i + 4]));
        }
        *(u16x8*)(og + orow) = st;
    }
}

// ---------- oproj K-loop (As: 64x256 swizzled tile, swapped) ----------
__device__ __forceinline__ void proj_mfma_loop_swap(
    const unsigned short* As, const unsigned short* Wt,
    int col0, int c, int g, f32x4 acc[4][4])
{
    short8 pb[4];
    #pragma unroll
    for (int n = 0; n < 4; ++n)
        pb[n] = *(const short8*)(Wt + (size_t)(col0 + n*16 + c) * 256 + g*8);

    #pragma unroll
    for (int step = 0; step < 8; ++step) {
        short8 b[4];
        #pragma unroll
        for (int n = 0; n < 4; ++n) b[n] = pb[n];
        if (step < 7) {
            int koff = (step + 1) * 32 + g * 8;
            #pragma unroll
            for (int n = 0; n < 4; ++n)
                pb[n] = *(const short8*)(Wt + (size_t)(col0 + n*16 + c) * 256 + koff);
        }
        short8 a[4];
        #pragma unroll
        for (int m = 0; m < 4; ++m) {
            int row = m * 16 + c;
            int off = row * 512 + ((step * 64 + g * 16) ^ ((row & 31) << 4));
            a[m] = *(const short8*)((const char*)As + off);
        }
        #pragma unroll
        for (int m = 0; m < 4; ++m)
            #pragma unroll
            for (int n = 0; n < 4; ++n)
                acc[m][n] = __builtin_amdgcn_mfma_f32_16x16x32_bf16(b[n], a[m], acc[m][n], 0, 0, 0);
    }
}

// ---------- kernel 3: output projection (LDS-staged og, swapped MFMA) ----------
__global__ __launch_bounds__(256) void oproj_kernel(
    const unsigned short* __restrict__ og, const unsigned short* __restrict__ wt_o,
    const float* __restrict__ bo, float* __restrict__ out)
{
    __shared__ __align__(16) unsigned short As[64 * 256];

    int row0 = blockIdx.x * 64;
    int tid = threadIdx.x;
    int lane = tid & 63;
    int c = lane & 15, g = lane >> 4;
    int col0 = (tid >> 6) * 64;

    #pragma unroll
    for (int j = 0; j < 8; ++j) {
        int idx = tid * 8 + j * 2048;
        int row = idx >> 8;
        int colB = (idx & 255) * 2;
        short8 v = *(const short8*)(og + (size_t)(row0 + row) * 256 + (idx & 255));
        int off = row * 512 + (colB ^ ((row & 31) << 4));
        *(short8*)((char*)As + off) = v;
    }
    __syncthreads();

    f32x4 acc[4][4];
    #pragma unroll
    for (int m = 0; m < 4; ++m)
        #pragma unroll
        for (int n = 0; n < 4; ++n)
            acc[m][n] = 0.0f;

    proj_mfma_loop_swap(As, wt_o, col0, c, g, acc);

    #pragma unroll
    for (int n = 0; n < 4; ++n) {
        int colb = col0 + n * 16 + 4 * g;
        f32x4 bov = *(const f32x4*)(bo + colb);
        #pragma unroll
        for (int m = 0; m < 4; ++m) {
            int row = row0 + m * 16 + c;
            f32x4 st = acc[m][n] + bov;
            *(f32x4*)(out + (size_t)row * 256 + colb) = st;
        }
    }
}

extern "C" void kernel_launch(void* const* d_in, const int* in_sizes, int n_in,
                              void* d_out, int out_size, void* d_ws, size_t ws_size,
                              hipStream_t stream) {
    const float* qx   = (const float*)d_in[0];
    const float* kx   = (const float*)d_in[1];
    const float* vx   = (const float*)d_in[2];
    const float* bias = (const float*)d_in[3];
    const float* Wq   = (const float*)d_in[4];
    const float* Wk   = (const float*)d_in[5];
    const float* Wv   = (const float*)d_in[6];
    const float* Wo   = (const float*)d_in[7];
    const float* bo   = (const float*)d_in[8];
    const float* Wg   = (const float*)d_in[9];
    const float* bg   = (const float*)d_in[10];

    uint8_t* ws = (uint8_t*)d_ws;
    unsigned short* wt = (unsigned short*)ws;                         // 640 KB
    unsigned short* Qa = (unsigned short*)(ws + (1u<<20));
    unsigned short* Ka = (unsigned short*)(ws + (1u<<20) + 1u*(1u<<24));
    unsigned short* Va = (unsigned short*)(ws + (1u<<20) + 2u*(1u<<24));
    unsigned short* G  = (unsigned short*)(ws + (1u<<20) + 3u*(1u<<24));
    unsigned short* og = (unsigned short*)(ws + (1u<<20) + 4u*(1u<<24));
    float*          bt = (float*)        (ws + (1u<<20) + 5u*(1u<<24)); // 2 MB

    hipLaunchKernelGGL(prep_kernel, dim3(208), dim3(256), 0, stream,
                       Wq, Wk, Wv, Wg, Wo, wt, bias, bt);
    hipLaunchKernelGGL(proj_kernel, dim3(512), dim3(512), 0, stream,
                       qx, kx, vx, bg, wt, Qa, Ka, Va, G);
    hipLaunchKernelGGL(attn_kernel, dim3(1024), dim3(512), 0, stream,
                       Qa, Ka, Va, G, bt, og);
    hipLaunchKernelGGL(oproj_kernel, dim3(512), dim3(256), 0, stream,
                       og, wt + 4*65536, bo, (float*)d_out);
}

// Round 22
// 106.711 us; speedup vs baseline: 1.3749x; 1.0031x over previous
//
#include <hip/hip_runtime.h>
#include <hip/hip_bf16.h>
#include <cstdint>
#include <cstddef>

typedef __attribute__((ext_vector_type(8))) short short8;
typedef __attribute__((ext_vector_type(4))) short s16x4;
typedef __attribute__((ext_vector_type(4))) unsigned short u16x4;
typedef __attribute__((ext_vector_type(8))) unsigned short u16x8;
typedef __attribute__((ext_vector_type(4))) float f32x4;
typedef __attribute__((ext_vector_type(4))) unsigned int u32x4;

__device__ __forceinline__ short bfbits(float f) {
    __bf16 h = (__bf16)f;
    return __builtin_bit_cast(short, h);
}
__device__ __forceinline__ float bf2f(unsigned short b) {
    union { uint32_t u; float f; } v; v.u = ((uint32_t)b) << 16;
    return v.f;
}
__device__ __forceinline__ unsigned int pack2(float x, float y) {
    return (unsigned int)(unsigned short)bfbits(x) |
           ((unsigned int)(unsigned short)bfbits(y) << 16);
}

// lgkmcnt-only barrier: makes ds_writes visible without draining vmcnt,
// so global loads issued before it stay in flight across the barrier (T4).
__device__ __forceinline__ void barrier_lgkm_only() {
    asm volatile("s_waitcnt lgkmcnt(0)" ::: "memory");
    __builtin_amdgcn_s_barrier();
}

// ---------- kernel 0: weight transpose + bias tiling (merged prep) ----------
__global__ __launch_bounds__(256) void prep_kernel(
    const float* __restrict__ Wq, const float* __restrict__ Wk,
    const float* __restrict__ Wv, const float* __restrict__ Wg,
    const float* __restrict__ Wo, unsigned short* __restrict__ wt,
    const float* __restrict__ bias, float* __restrict__ bt)
{
    int bid = blockIdx.x;
    int tid = threadIdx.x;
    if (bid < 80) {
        int mat  = bid >> 4;
        int tile = bid & 15;
        int k0 = (tile >> 2) * 64, n0 = (tile & 3) * 64;
        const float* W = (mat==0)?Wq:(mat==1)?Wk:(mat==2)?Wv:(mat==3)?Wg:Wo;
        __shared__ unsigned short T[64][72];   // T[n][k]
        int tx = tid & 15, ty = tid >> 4;
        #pragma unroll
        for (int j = 0; j < 4; ++j) {
            int kr = ty + j*16;
            f32x4 v = *(const f32x4*)(W + (size_t)(k0+kr)*256 + n0 + tx*4);
            #pragma unroll
            for (int e = 0; e < 4; ++e) T[tx*4+e][kr] = (unsigned short)bfbits(v[e]);
        }
        __syncthreads();
        #pragma unroll
        for (int j = 0; j < 4; ++j) {
            int nr = ty + j*16;
            int kk = k0 + tx*4;
            int dstk = kk;
            if (mat == 4) {
                // sigma within each 32-block of k: 4a+e -> 8a+e (a<4), 16+4g+e -> 8g+4+e
                int a = (kk >> 2) & 7;
                int hb = kk & ~31;
                dstk = hb + ((a < 4) ? 8*a : 8*(a-4) + 4);
            }
            u16x4 st;
            #pragma unroll
            for (int e = 0; e < 4; ++e) st[e] = T[nr][tx*4+e];
            *(u16x4*)(wt + ((size_t)mat*256 + n0+nr)*256 + dstk) = st;
        }
    } else {
        int hb = bid - 80;          // 0..127 = h*16 + qt
        int h = hb >> 4, qt = hb & 15;
        int cc = tid >> 4, n = tid & 15;
        const float* src = bias + ((size_t)(h*256 + qt*16 + cc))*256 + n*16;
        float* dst = bt + ((size_t)(hb*16 + n))*256 + cc*16;
        #pragma unroll
        for (int q = 0; q < 4; ++q)
            *(f32x4*)(dst + q*4) = *(const f32x4*)(src + q*4);
    }
}

// ---------- proj K-loop, 2 col-tiles/wave (depth-1 weight prefetch) ----------
// As: 64x256 bf16 tile, row stride 512 B, byte-col XOR ((row&31)<<4).
template<int SWAP>
__device__ __forceinline__ void proj_mfma_loop2(
    const unsigned short* As, const unsigned short* Wt,
    int col0, int c, int g, f32x4 acc[4][2])
{
    short8 pb[2];
    #pragma unroll
    for (int n = 0; n < 2; ++n)
        pb[n] = *(const short8*)(Wt + (size_t)(col0 + n*16 + c) * 256 + g*8);

    __builtin_amdgcn_s_setprio(1);
    #pragma unroll
    for (int step = 0; step < 8; ++step) {
        short8 b[2];
        #pragma unroll
        for (int n = 0; n < 2; ++n) b[n] = pb[n];
        if (step < 7) {
            int koff = (step + 1) * 32 + g * 8;
            #pragma unroll
            for (int n = 0; n < 2; ++n)
                pb[n] = *(const short8*)(Wt + (size_t)(col0 + n*16 + c) * 256 + koff);
        }
        short8 a[4];
        #pragma unroll
        for (int m = 0; m < 4; ++m) {
            int row = m * 16 + c;
            int off = row * 512 + ((step * 64 + g * 16) ^ ((row & 31) << 4));
            a[m] = *(const short8*)((const char*)As + off);
        }
        #pragma unroll
        for (int m = 0; m < 4; ++m)
            #pragma unroll
            for (int n = 0; n < 2; ++n) {
                if (SWAP)
                    acc[m][n] = __builtin_amdgcn_mfma_f32_16x16x32_bf16(b[n], a[m], acc[m][n], 0, 0, 0);
                else
                    acc[m][n] = __builtin_amdgcn_mfma_f32_16x16x32_bf16(a[m], b[n], acc[m][n], 0, 0, 0);
            }
    }
    __builtin_amdgcn_s_setprio(0);
}

// ---------- kernel 1: projections, 3-phase pipeline with async loads ----------
// Phase t: {pack prev loads -> ds_write LDS[t&1]; issue next loads;
//           lgkm-only barrier (loads stay in flight); compute}.
__global__ __launch_bounds__(512, 2) void proj_kernel(
    const float* __restrict__ qx, const float* __restrict__ kx, const float* __restrict__ vx,
    const float* __restrict__ bg, const unsigned short* __restrict__ wt,
    unsigned short* __restrict__ Qa, unsigned short* __restrict__ Ka,
    unsigned short* __restrict__ Va, unsigned short* __restrict__ G)
{
    __shared__ __align__(16) unsigned short As[2][64 * 256];   // 2 x 32 KB

    int rb = blockIdx.x;
    int row0 = rb * 64;
    int tid = threadIdx.x;
    int w = tid >> 6, lane = tid & 63;
    int c = lane & 15, g = lane >> 4;
    int col0 = w * 32;
    int l32 = tid & 31, rg = tid >> 5;      // staging coords
    int r_ = row0 >> 8;
    int s0b = row0 & 255;
    int h_ = col0 >> 5;                     // one head per wave

    f32x4 ld[8];                            // raw f32 tile in flight (32 VGPR)

    // prologue: issue qx loads
    #pragma unroll
    for (int j = 0; j < 4; ++j) {
        const float* src = qx + (size_t)(row0 + j*16 + rg) * 256 + l32 * 8;
        ld[2*j]   = *(const f32x4*)src;
        ld[2*j+1] = *(const f32x4*)(src + 4);
    }

    // ================= phase 0: Q + G from qx =================
    #pragma unroll
    for (int j = 0; j < 4; ++j) {
        int row = j*16 + rg;
        u32x4 pkv;
        pkv[0] = pack2(ld[2*j][0],   ld[2*j][1]);   pkv[1] = pack2(ld[2*j][2],   ld[2*j][3]);
        pkv[2] = pack2(ld[2*j+1][0], ld[2*j+1][1]); pkv[3] = pack2(ld[2*j+1][2], ld[2*j+1][3]);
        int off = row * 512 + ((l32 * 16) ^ ((row & 31) << 4));
        *(u32x4*)((char*)&As[0][0] + off) = pkv;
    }
    // issue kx loads (stay in flight across barrier; first use = phase-1 pack)
    #pragma unroll
    for (int j = 0; j < 4; ++j) {
        const float* src = kx + (size_t)(row0 + j*16 + rg) * 256 + l32 * 8;
        ld[2*j]   = *(const f32x4*)src;
        ld[2*j+1] = *(const f32x4*)(src + 4);
    }
    barrier_lgkm_only();
    {
        f32x4 acc[4][2];
        #pragma unroll
        for (int m = 0; m < 4; ++m)
            #pragma unroll
            for (int n = 0; n < 2; ++n) acc[m][n] = 0.0f;
        proj_mfma_loop2<1>(&As[0][0], wt, col0, c, g, acc);
        #pragma unroll
        for (int m = 0; m < 4; ++m) {
            int s_ = s0b + m * 16 + c;
            u16x8 st;
            #pragma unroll
            for (int i = 0; i < 4; ++i) {
                st[i]     = (unsigned short)bfbits(acc[m][0][i]);
                st[i + 4] = (unsigned short)bfbits(acc[m][1][i]);
            }
            *(u16x8*)(Qa + ((size_t)((r_*8 + h_)*256 + s_)) * 32 + 8*g) = st;
        }
        // G
        #pragma unroll
        for (int m = 0; m < 4; ++m)
            #pragma unroll
            for (int n = 0; n < 2; ++n) acc[m][n] = 0.0f;
        proj_mfma_loop2<1>(&As[0][0], wt + 3*65536, col0, c, g, acc);
        f32x4 bg0 = *(const f32x4*)(bg + col0 + 4*g);
        f32x4 bg1 = *(const f32x4*)(bg + col0 + 16 + 4*g);
        #pragma unroll
        for (int m = 0; m < 4; ++m) {
            int rq = row0 + m * 16 + c;
            u16x8 st;
            #pragma unroll
            for (int i = 0; i < 4; ++i) {
                float sa = 1.0f / (1.0f + __expf(-(acc[m][0][i] + bg0[i])));
                float sb = 1.0f / (1.0f + __expf(-(acc[m][1][i] + bg1[i])));
                st[i]     = (unsigned short)bfbits(sa);
                st[i + 4] = (unsigned short)bfbits(sb);
            }
            *(u16x8*)(G + (size_t)rq * 256 + col0 + 8*g) = st;
        }
    }

    // ================= phase 1: K from kx =================
    #pragma unroll
    for (int j = 0; j < 4; ++j) {
        int row = j*16 + rg;
        u32x4 pkv;
        pkv[0] = pack2(ld[2*j][0],   ld[2*j][1]);   pkv[1] = pack2(ld[2*j][2],   ld[2*j][3]);
        pkv[2] = pack2(ld[2*j+1][0], ld[2*j+1][1]); pkv[3] = pack2(ld[2*j+1][2], ld[2*j+1][3]);
        int off = row * 512 + ((l32 * 16) ^ ((row & 31) << 4));
        *(u32x4*)((char*)&As[1][0] + off) = pkv;
    }
    // issue vx loads
    #pragma unroll
    for (int j = 0; j < 4; ++j) {
        const float* src = vx + (size_t)(row0 + j*16 + rg) * 256 + l32 * 8;
        ld[2*j]   = *(const f32x4*)src;
        ld[2*j+1] = *(const f32x4*)(src + 4);
    }
    barrier_lgkm_only();
    {
        f32x4 acc[4][2];
        #pragma unroll
        for (int m = 0; m < 4; ++m)
            #pragma unroll
            for (int n = 0; n < 2; ++n) acc[m][n] = 0.0f;
        proj_mfma_loop2<1>(&As[1][0], wt + 65536, col0, c, g, acc);
        #pragma unroll
        for (int m = 0; m < 4; ++m) {
            int s_ = s0b + m * 16 + c;
            u16x8 st;
            #pragma unroll
            for (int i = 0; i < 4; ++i) {
                st[i]     = (unsigned short)bfbits(acc[m][0][i]);
                st[i + 4] = (unsigned short)bfbits(acc[m][1][i]);
            }
            *(u16x8*)(Ka + ((size_t)((r_*8 + h_)*256 + s_)) * 32 + 8*g) = st;
        }
    }

    // ================= phase 2: V from vx =================
    // WAR-safe: every wave finished phase-0's LDS[0] reads before phase-1's barrier.
    #pragma unroll
    for (int j = 0; j < 4; ++j) {
        int row = j*16 + rg;
        u32x4 pkv;
        pkv[0] = pack2(ld[2*j][0],   ld[2*j][1]);   pkv[1] = pack2(ld[2*j][2],   ld[2*j][3]);
        pkv[2] = pack2(ld[2*j+1][0], ld[2*j+1][1]); pkv[3] = pack2(ld[2*j+1][2], ld[2*j+1][3]);
        int off = row * 512 + ((l32 * 16) ^ ((row & 31) << 4));
        *(u32x4*)((char*)&As[0][0] + off) = pkv;
    }
    barrier_lgkm_only();
    {
        f32x4 acc[4][2];
        #pragma unroll
        for (int m = 0; m < 4; ++m)
            #pragma unroll
            for (int n = 0; n < 2; ++n) acc[m][n] = 0.0f;
        proj_mfma_loop2<0>(&As[0][0], wt + 2*65536, col0, c, g, acc);
        #pragma unroll
        for (int n = 0; n < 2; ++n) {
            int d_ = n*16 + c;
            size_t rowbase = ((size_t)((r_*8 + h_)*32 + d_)) * 256;
            #pragma unroll
            for (int p = 0; p < 2; ++p) {    // m-pairs (0,1),(2,3) -> tau slots
                u16x8 st;
                #pragma unroll
                for (int i = 0; i < 4; ++i) {
                    st[i]     = (unsigned short)bfbits(acc[2*p][n][i]);
                    st[i + 4] = (unsigned short)bfbits(acc[2*p+1][n][i]);
                }
                *(u16x8*)(Va + rowbase + s0b + 32*p + 8*g) = st;
            }
        }
    }
}

// ---------- kernel 2: attention, one block per (r,h), K/V in LDS ----------
// qq loop unrolled (ILP across q-tiles) + s_setprio around MFMA core (T5).
__global__ __launch_bounds__(512) void attn_kernel(
    const unsigned short* __restrict__ Qa, const unsigned short* __restrict__ Ka,
    const unsigned short* __restrict__ Va, const unsigned short* __restrict__ G,
    const float* __restrict__ bt, unsigned short* __restrict__ og)
{
    __shared__ __align__(16) unsigned short Ks[256 * 40];  // [s][d'] pad 40
    __shared__ __align__(16) unsigned short Vs[32 * 264];  // [d][s'=slot] pad 264

    int rh = blockIdx.x;            // 0..1023
    int r = rh >> 3, h = rh & 7;
    int tid = threadIdx.x;          // 512 threads
    int w = tid >> 6, lane = tid & 63;
    int c = lane & 15, g = lane >> 4;
    size_t base = (size_t)rh * 8192;

    #pragma unroll
    for (int j = 0; j < 2; ++j) {
        int idx8 = (tid + j*512) * 8;
        int s_ = idx8 >> 5, d_ = idx8 & 31;
        short8 v = *(const short8*)(Ka + base + idx8);
        *(short8*)(&Ks[s_*40 + d_]) = v;
    }
    #pragma unroll
    for (int j = 0; j < 2; ++j) {
        int idx8 = (tid + j*512) * 8;
        int d_ = idx8 >> 8, s0 = idx8 & 255;
        short8 v = *(const short8*)(Va + base + idx8);
        *(short8*)(&Vs[d_*264 + s0]) = v;
    }
    __syncthreads();

    const float* bth = bt + (size_t)h * 65536;
    const float nrmv = 0.17677669529663687f;

    #pragma unroll
    for (int qq = 0; qq < 2; ++qq) {
        int qt = w*2 + qq;                 // 0..15
        int qrow = qt * 16;
        short8 qf = *(const short8*)(Qa + base + (size_t)(qrow + c)*32 + g*8);
        const float* btt = bth + (size_t)qt*4096 + (c*4 + g)*4;

        f32x4 o0 = 0.0f, o1 = 0.0f;
        float sum = 0.f;
        __builtin_amdgcn_s_setprio(1);
        #pragma unroll
        for (int t = 0; t < 8; ++t) {
            int n0 = 2*t, n1 = 2*t + 1;
            short8 kf0 = *(const short8*)(&Ks[(n0*16 + c)*40 + g*8]);
            short8 kf1 = *(const short8*)(&Ks[(n1*16 + c)*40 + g*8]);
            f32x4 bv0 = *(const f32x4*)(btt + n0*256);
            f32x4 bv1 = *(const f32x4*)(btt + n1*256);
            f32x4 z = 0.0f;
            f32x4 s0 = __builtin_amdgcn_mfma_f32_16x16x32_bf16(kf0, qf, z, 0, 0, 0);
            f32x4 s1 = __builtin_amdgcn_mfma_f32_16x16x32_bf16(kf1, qf, z, 0, 0, 0);
            float e0 = __expf(fmaf(s0[0], nrmv, bv0[0]));
            float e1 = __expf(fmaf(s0[1], nrmv, bv0[1]));
            float e2 = __expf(fmaf(s0[2], nrmv, bv0[2]));
            float e3 = __expf(fmaf(s0[3], nrmv, bv0[3]));
            float e4 = __expf(fmaf(s1[0], nrmv, bv1[0]));
            float e5 = __expf(fmaf(s1[1], nrmv, bv1[1]));
            float e6 = __expf(fmaf(s1[2], nrmv, bv1[2]));
            float e7 = __expf(fmaf(s1[3], nrmv, bv1[3]));
            sum += ((e0+e1)+(e2+e3)) + ((e4+e5)+(e6+e7));
            u32x4 aw;
            aw[0] = pack2(e0, e1); aw[1] = pack2(e2, e3);
            aw[2] = pack2(e4, e5); aw[3] = pack2(e6, e7);
            short8 pfrag = __builtin_bit_cast(short8, aw);
            short8 va0 = *(const short8*)(&Vs[(c)*264      + t*32 + g*8]);
            short8 va1 = *(const short8*)(&Vs[(16 + c)*264 + t*32 + g*8]);
            o0 = __builtin_amdgcn_mfma_f32_16x16x32_bf16(va0, pfrag, o0, 0, 0, 0);
            o1 = __builtin_amdgcn_mfma_f32_16x16x32_bf16(va1, pfrag, o1, 0, 0, 0);
        }
        __builtin_amdgcn_s_setprio(0);
        sum += __shfl_xor(sum, 16);
        sum += __shfl_xor(sum, 32);
        float inv = 1.0f / sum;

        size_t orow = ((size_t)(r*256 + qrow + c)) * 256 + h*32 + 8*g;
        u16x8 gv = *(const u16x8*)(G + orow);
        u16x8 st;
        #pragma unroll
        for (int i = 0; i < 4; ++i) {
            st[i]     = (unsigned short)bfbits(o0[i] * inv * bf2f(gv[i]));
            st[i + 4] = (unsigned short)bfbits(o1[i] * inv * bf2f(gv[i + 4]));
        }
        *(u16x8*)(og + orow) = st;
    }
}

// ---------- oproj K-loop (As: 64x256 swizzled tile, swapped) ----------
__device__ __forceinline__ void proj_mfma_loop_swap(
    const unsigned short* As, const unsigned short* Wt,
    int col0, int c, int g, f32x4 acc[4][4])
{
    short8 pb[4];
    #pragma unroll
    for (int n = 0; n < 4; ++n)
        pb[n] = *(const short8*)(Wt + (size_t)(col0 + n*16 + c) * 256 + g*8);

    __builtin_amdgcn_s_setprio(1);
    #pragma unroll
    for (int step = 0; step < 8; ++step) {
        short8 b[4];
        #pragma unroll
        for (int n = 0; n < 4; ++n) b[n] = pb[n];
        if (step < 7) {
            int koff = (step + 1) * 32 + g * 8;
            #pragma unroll
            for (int n = 0; n < 4; ++n)
                pb[n] = *(const short8*)(Wt + (size_t)(col0 + n*16 + c) * 256 + koff);
        }
        short8 a[4];
        #pragma unroll
        for (int m = 0; m < 4; ++m) {
            int row = m * 16 + c;
            int off = row * 512 + ((step * 64 + g * 16) ^ ((row & 31) << 4));
            a[m] = *(const short8*)((const char*)As + off);
        }
        #pragma unroll
        for (int m = 0; m < 4; ++m)
            #pragma unroll
            for (int n = 0; n < 4; ++n)
                acc[m][n] = __builtin_amdgcn_mfma_f32_16x16x32_bf16(b[n], a[m], acc[m][n], 0, 0, 0);
    }
    __builtin_amdgcn_s_setprio(0);
}

// ---------- kernel 3: output projection (LDS-staged og, swapped MFMA) ----------
__global__ __launch_bounds__(256) void oproj_kernel(
    const unsigned short* __restrict__ og, const unsigned short* __restrict__ wt_o,
    const float* __restrict__ bo, float* __restrict__ out)
{
    __shared__ __align__(16) unsigned short As[64 * 256];

    int row0 = blockIdx.x * 64;
    int tid = threadIdx.x;
    int lane = tid & 63;
    int c = lane & 15, g = lane >> 4;
    int col0 = (tid >> 6) * 64;

    #pragma unroll
    for (int j = 0; j < 8; ++j) {
        int idx = tid * 8 + j * 2048;
        int row = idx >> 8;
        int colB = (idx & 255) * 2;
        short8 v = *(const short8*)(og + (size_t)(row0 + row) * 256 + (idx & 255));
        int off = row * 512 + (colB ^ ((row & 31) << 4));
        *(short8*)((char*)As + off) = v;
    }
    __syncthreads();

    f32x4 acc[4][4];
    #pragma unroll
    for (int m = 0; m < 4; ++m)
        #pragma unroll
        for (int n = 0; n < 4; ++n)
            acc[m][n] = 0.0f;

    proj_mfma_loop_swap(As, wt_o, col0, c, g, acc);

    #pragma unroll
    for (int n = 0; n < 4; ++n) {
        int colb = col0 + n * 16 + 4 * g;
        f32x4 bov = *(const f32x4*)(bo + colb);
        #pragma unroll
        for (int m = 0; m < 4; ++m) {
            int row = row0 + m * 16 + c;
            f32x4 st = acc[m][n] + bov;
            *(f32x4*)(out + (size_t)row * 256 + colb) = st;
        }
    }
}

extern "C" void kernel_launch(void* const* d_in, const int* in_sizes, int n_in,
                              void* d_out, int out_size, void* d_ws, size_t ws_size,
                              hipStream_t stream) {
    const float* qx   = (const float*)d_in[0];
    const float* kx   = (const float*)d_in[1];
    const float* vx   = (const float*)d_in[2];
    const float* bias = (const float*)d_in[3];
    const float* Wq   = (const float*)d_in[4];
    const float* Wk   = (const float*)d_in[5];
    const float* Wv   = (const float*)d_in[6];
    const float* Wo   = (const float*)d_in[7];
    const float* bo   = (const float*)d_in[8];
    const float* Wg   = (const float*)d_in[9];
    const float* bg   = (const float*)d_in[10];

    uint8_t* ws = (uint8_t*)d_ws;
    unsigned short* wt = (unsigned short*)ws;                         // 640 KB
    unsigned short* Qa = (unsigned short*)(ws + (1u<<20));
    unsigned short* Ka = (unsigned short*)(ws + (1u<<20) + 1u*(1u<<24));
    unsigned short* Va = (unsigned short*)(ws + (1u<<20) + 2u*(1u<<24));
    unsigned short* G  = (unsigned short*)(ws + (1u<<20) + 3u*(1u<<24));
    unsigned short* og = (unsigned short*)(ws + (1u<<20) + 4u*(1u<<24));
    float*          bt = (float*)        (ws + (1u<<20) + 5u*(1u<<24)); // 2 MB

    hipLaunchKernelGGL(prep_kernel, dim3(208), dim3(256), 0, stream,
                       Wq, Wk, Wv, Wg, Wo, wt, bias, bt);
    hipLaunchKernelGGL(proj_kernel, dim3(512), dim3(512), 0, stream,
                       qx, kx, vx, bg, wt, Qa, Ka, Va, G);
    hipLaunchKernelGGL(attn_kernel, dim3(1024), dim3(512), 0, stream,
                       Qa, Ka, Va, G, bt, og);
    hipLaunchKernelGGL(oproj_kernel, dim3(512), dim3(256), 0, stream,
                       og, wt + 4*65536, bo, (float*)d_out);
}

// Round 23
// 106.679 us; speedup vs baseline: 1.3753x; 1.0003x over previous
//
#include <hip/hip_runtime.h>
#include <hip/hip_bf16.h>
#include <cstdint>
#include <cstddef>

typedef __attribute__((ext_vector_type(8))) short short8;
typedef __attribute__((ext_vector_type(4))) short s16x4;
typedef __attribute__((ext_vector_type(4))) unsigned short u16x4;
typedef __attribute__((ext_vector_type(8))) unsigned short u16x8;
typedef __attribute__((ext_vector_type(4))) float f32x4;
typedef __attribute__((ext_vector_type(4))) unsigned int u32x4;

__device__ __forceinline__ short bfbits(float f) {
    __bf16 h = (__bf16)f;
    return __builtin_bit_cast(short, h);
}
__device__ __forceinline__ float bf2f(unsigned short b) {
    union { uint32_t u; float f; } v; v.u = ((uint32_t)b) << 16;
    return v.f;
}
__device__ __forceinline__ unsigned int pack2(float x, float y) {
    return (unsigned int)(unsigned short)bfbits(x) |
           ((unsigned int)(unsigned short)bfbits(y) << 16);
}

// lgkmcnt-only barrier: makes ds_writes visible without draining vmcnt,
// so global loads issued before it stay in flight across the barrier (T4).
__device__ __forceinline__ void barrier_lgkm_only() {
    asm volatile("s_waitcnt lgkmcnt(0)" ::: "memory");
    __builtin_amdgcn_s_barrier();
}

// ---------- kernel 0: weight transpose + bias tiling (merged prep) ----------
__global__ __launch_bounds__(256) void prep_kernel(
    const float* __restrict__ Wq, const float* __restrict__ Wk,
    const float* __restrict__ Wv, const float* __restrict__ Wg,
    const float* __restrict__ Wo, unsigned short* __restrict__ wt,
    const float* __restrict__ bias, float* __restrict__ bt)
{
    int bid = blockIdx.x;
    int tid = threadIdx.x;
    if (bid < 80) {
        int mat  = bid >> 4;
        int tile = bid & 15;
        int k0 = (tile >> 2) * 64, n0 = (tile & 3) * 64;
        const float* W = (mat==0)?Wq:(mat==1)?Wk:(mat==2)?Wv:(mat==3)?Wg:Wo;
        __shared__ unsigned short T[64][72];   // T[n][k]
        int tx = tid & 15, ty = tid >> 4;
        #pragma unroll
        for (int j = 0; j < 4; ++j) {
            int kr = ty + j*16;
            f32x4 v = *(const f32x4*)(W + (size_t)(k0+kr)*256 + n0 + tx*4);
            #pragma unroll
            for (int e = 0; e < 4; ++e) T[tx*4+e][kr] = (unsigned short)bfbits(v[e]);
        }
        __syncthreads();
        #pragma unroll
        for (int j = 0; j < 4; ++j) {
            int nr = ty + j*16;
            int kk = k0 + tx*4;
            int dstk = kk;
            if (mat == 4) {
                // sigma within each 32-block of k: 4a+e -> 8a+e (a<4), 16+4g+e -> 8g+4+e
                int a = (kk >> 2) & 7;
                int hb = kk & ~31;
                dstk = hb + ((a < 4) ? 8*a : 8*(a-4) + 4);
            }
            u16x4 st;
            #pragma unroll
            for (int e = 0; e < 4; ++e) st[e] = T[nr][tx*4+e];
            *(u16x4*)(wt + ((size_t)mat*256 + n0+nr)*256 + dstk) = st;
        }
    } else {
        int hb = bid - 80;          // 0..127 = h*16 + qt
        int h = hb >> 4, qt = hb & 15;
        int cc = tid >> 4, n = tid & 15;
        const float* src = bias + ((size_t)(h*256 + qt*16 + cc))*256 + n*16;
        float* dst = bt + ((size_t)(hb*16 + n))*256 + cc*16;
        #pragma unroll
        for (int q = 0; q < 4; ++q)
            *(f32x4*)(dst + q*4) = *(const f32x4*)(src + q*4);
    }
}

// ---------- proj K-loop, 2 col-tiles/wave, depth-4 rolling weight prefetch ----------
// As: 64x256 bf16 tile, row stride 512 B, byte-col XOR ((row&31)<<4).
template<int SWAP>
__device__ __forceinline__ void proj_mfma_loop2(
    const unsigned short* As, const unsigned short* Wt,
    int col0, int c, int g, f32x4 acc[4][2])
{
    short8 pb[4][2];
    #pragma unroll
    for (int s = 0; s < 4; ++s)
        #pragma unroll
        for (int n = 0; n < 2; ++n)
            pb[s][n] = *(const short8*)(Wt + (size_t)(col0 + n*16 + c) * 256 + s*32 + g*8);

    __builtin_amdgcn_s_setprio(1);
    #pragma unroll
    for (int step = 0; step < 8; ++step) {
        short8 b[2];
        #pragma unroll
        for (int n = 0; n < 2; ++n) b[n] = pb[step & 3][n];
        if (step < 4) {
            int koff = (step + 4) * 32 + g * 8;
            #pragma unroll
            for (int n = 0; n < 2; ++n)
                pb[step & 3][n] = *(const short8*)(Wt + (size_t)(col0 + n*16 + c) * 256 + koff);
        }
        short8 a[4];
        #pragma unroll
        for (int m = 0; m < 4; ++m) {
            int row = m * 16 + c;
            int off = row * 512 + ((step * 64 + g * 16) ^ ((row & 31) << 4));
            a[m] = *(const short8*)((const char*)As + off);
        }
        #pragma unroll
        for (int m = 0; m < 4; ++m)
            #pragma unroll
            for (int n = 0; n < 2; ++n) {
                if (SWAP)
                    acc[m][n] = __builtin_amdgcn_mfma_f32_16x16x32_bf16(b[n], a[m], acc[m][n], 0, 0, 0);
                else
                    acc[m][n] = __builtin_amdgcn_mfma_f32_16x16x32_bf16(a[m], b[n], acc[m][n], 0, 0, 0);
            }
    }
    __builtin_amdgcn_s_setprio(0);
}

// ---------- kernel 1: projections, 3-phase pipeline with async loads ----------
// Phase t: {pack prev loads -> ds_write LDS[t&1]; issue next loads;
//           lgkm-only barrier (loads stay in flight); compute}.
__global__ __launch_bounds__(512, 2) void proj_kernel(
    const float* __restrict__ qx, const float* __restrict__ kx, const float* __restrict__ vx,
    const float* __restrict__ bg, const unsigned short* __restrict__ wt,
    unsigned short* __restrict__ Qa, unsigned short* __restrict__ Ka,
    unsigned short* __restrict__ Va, unsigned short* __restrict__ G)
{
    __shared__ __align__(16) unsigned short As[2][64 * 256];   // 2 x 32 KB

    int rb = blockIdx.x;
    int row0 = rb * 64;
    int tid = threadIdx.x;
    int w = tid >> 6, lane = tid & 63;
    int c = lane & 15, g = lane >> 4;
    int col0 = w * 32;
    int l32 = tid & 31, rg = tid >> 5;      // staging coords
    int r_ = row0 >> 8;
    int s0b = row0 & 255;
    int h_ = col0 >> 5;                     // one head per wave

    f32x4 ld[8];                            // raw f32 tile in flight (32 VGPR)

    // prologue: issue qx loads
    #pragma unroll
    for (int j = 0; j < 4; ++j) {
        const float* src = qx + (size_t)(row0 + j*16 + rg) * 256 + l32 * 8;
        ld[2*j]   = *(const f32x4*)src;
        ld[2*j+1] = *(const f32x4*)(src + 4);
    }

    // ================= phase 0: Q + G from qx =================
    #pragma unroll
    for (int j = 0; j < 4; ++j) {
        int row = j*16 + rg;
        u32x4 pkv;
        pkv[0] = pack2(ld[2*j][0],   ld[2*j][1]);   pkv[1] = pack2(ld[2*j][2],   ld[2*j][3]);
        pkv[2] = pack2(ld[2*j+1][0], ld[2*j+1][1]); pkv[3] = pack2(ld[2*j+1][2], ld[2*j+1][3]);
        int off = row * 512 + ((l32 * 16) ^ ((row & 31) << 4));
        *(u32x4*)((char*)&As[0][0] + off) = pkv;
    }
    // issue kx loads (stay in flight across barrier; first use = phase-1 pack)
    #pragma unroll
    for (int j = 0; j < 4; ++j) {
        const float* src = kx + (size_t)(row0 + j*16 + rg) * 256 + l32 * 8;
        ld[2*j]   = *(const f32x4*)src;
        ld[2*j+1] = *(const f32x4*)(src + 4);
    }
    barrier_lgkm_only();
    {
        f32x4 acc[4][2];
        #pragma unroll
        for (int m = 0; m < 4; ++m)
            #pragma unroll
            for (int n = 0; n < 2; ++n) acc[m][n] = 0.0f;
        proj_mfma_loop2<1>(&As[0][0], wt, col0, c, g, acc);
        #pragma unroll
        for (int m = 0; m < 4; ++m) {
            int s_ = s0b + m * 16 + c;
            u16x8 st;
            #pragma unroll
            for (int i = 0; i < 4; ++i) {
                st[i]     = (unsigned short)bfbits(acc[m][0][i]);
                st[i + 4] = (unsigned short)bfbits(acc[m][1][i]);
            }
            *(u16x8*)(Qa + ((size_t)((r_*8 + h_)*256 + s_)) * 32 + 8*g) = st;
        }
        // G
        #pragma unroll
        for (int m = 0; m < 4; ++m)
            #pragma unroll
            for (int n = 0; n < 2; ++n) acc[m][n] = 0.0f;
        proj_mfma_loop2<1>(&As[0][0], wt + 3*65536, col0, c, g, acc);
        f32x4 bg0 = *(const f32x4*)(bg + col0 + 4*g);
        f32x4 bg1 = *(const f32x4*)(bg + col0 + 16 + 4*g);
        #pragma unroll
        for (int m = 0; m < 4; ++m) {
            int rq = row0 + m * 16 + c;
            u16x8 st;
            #pragma unroll
            for (int i = 0; i < 4; ++i) {
                float sa = 1.0f / (1.0f + __expf(-(acc[m][0][i] + bg0[i])));
                float sb = 1.0f / (1.0f + __expf(-(acc[m][1][i] + bg1[i])));
                st[i]     = (unsigned short)bfbits(sa);
                st[i + 4] = (unsigned short)bfbits(sb);
            }
            *(u16x8*)(G + (size_t)rq * 256 + col0 + 8*g) = st;
        }
    }

    // ================= phase 1: K from kx =================
    #pragma unroll
    for (int j = 0; j < 4; ++j) {
        int row = j*16 + rg;
        u32x4 pkv;
        pkv[0] = pack2(ld[2*j][0],   ld[2*j][1]);   pkv[1] = pack2(ld[2*j][2],   ld[2*j][3]);
        pkv[2] = pack2(ld[2*j+1][0], ld[2*j+1][1]); pkv[3] = pack2(ld[2*j+1][2], ld[2*j+1][3]);
        int off = row * 512 + ((l32 * 16) ^ ((row & 31) << 4));
        *(u32x4*)((char*)&As[1][0] + off) = pkv;
    }
    // issue vx loads
    #pragma unroll
    for (int j = 0; j < 4; ++j) {
        const float* src = vx + (size_t)(row0 + j*16 + rg) * 256 + l32 * 8;
        ld[2*j]   = *(const f32x4*)src;
        ld[2*j+1] = *(const f32x4*)(src + 4);
    }
    barrier_lgkm_only();
    {
        f32x4 acc[4][2];
        #pragma unroll
        for (int m = 0; m < 4; ++m)
            #pragma unroll
            for (int n = 0; n < 2; ++n) acc[m][n] = 0.0f;
        proj_mfma_loop2<1>(&As[1][0], wt + 65536, col0, c, g, acc);
        #pragma unroll
        for (int m = 0; m < 4; ++m) {
            int s_ = s0b + m * 16 + c;
            u16x8 st;
            #pragma unroll
            for (int i = 0; i < 4; ++i) {
                st[i]     = (unsigned short)bfbits(acc[m][0][i]);
                st[i + 4] = (unsigned short)bfbits(acc[m][1][i]);
            }
            *(u16x8*)(Ka + ((size_t)((r_*8 + h_)*256 + s_)) * 32 + 8*g) = st;
        }
    }

    // ================= phase 2: V from vx =================
    // WAR-safe: every wave finished phase-0's LDS[0] reads before phase-1's barrier.
    #pragma unroll
    for (int j = 0; j < 4; ++j) {
        int row = j*16 + rg;
        u32x4 pkv;
        pkv[0] = pack2(ld[2*j][0],   ld[2*j][1]);   pkv[1] = pack2(ld[2*j][2],   ld[2*j][3]);
        pkv[2] = pack2(ld[2*j+1][0], ld[2*j+1][1]); pkv[3] = pack2(ld[2*j+1][2], ld[2*j+1][3]);
        int off = row * 512 + ((l32 * 16) ^ ((row & 31) << 4));
        *(u32x4*)((char*)&As[0][0] + off) = pkv;
    }
    barrier_lgkm_only();
    {
        f32x4 acc[4][2];
        #pragma unroll
        for (int m = 0; m < 4; ++m)
            #pragma unroll
            for (int n = 0; n < 2; ++n) acc[m][n] = 0.0f;
        proj_mfma_loop2<0>(&As[0][0], wt + 2*65536, col0, c, g, acc);
        #pragma unroll
        for (int n = 0; n < 2; ++n) {
            int d_ = n*16 + c;
            size_t rowbase = ((size_t)((r_*8 + h_)*32 + d_)) * 256;
            #pragma unroll
            for (int p = 0; p < 2; ++p) {    // m-pairs (0,1),(2,3) -> tau slots
                u16x8 st;
                #pragma unroll
                for (int i = 0; i < 4; ++i) {
                    st[i]     = (unsigned short)bfbits(acc[2*p][n][i]);
                    st[i + 4] = (unsigned short)bfbits(acc[2*p+1][n][i]);
                }
                *(u16x8*)(Va + rowbase + s0b + 32*p + 8*g) = st;
            }
        }
    }
}

// ---------- kernel 2: attention, one block per (r,h), K/V in LDS ----------
// qq loop unrolled (ILP across q-tiles) + s_setprio around MFMA core (T5).
__global__ __launch_bounds__(512) void attn_kernel(
    const unsigned short* __restrict__ Qa, const unsigned short* __restrict__ Ka,
    const unsigned short* __restrict__ Va, const unsigned short* __restrict__ G,
    const float* __restrict__ bt, unsigned short* __restrict__ og)
{
    __shared__ __align__(16) unsigned short Ks[256 * 40];  // [s][d'] pad 40
    __shared__ __align__(16) unsigned short Vs[32 * 264];  // [d][s'=slot] pad 264

    int rh = blockIdx.x;            // 0..1023
    int r = rh >> 3, h = rh & 7;
    int tid = threadIdx.x;          // 512 threads
    int w = tid >> 6, lane = tid & 63;
    int c = lane & 15, g = lane >> 4;
    size_t base = (size_t)rh * 8192;

    #pragma unroll
    for (int j = 0; j < 2; ++j) {
        int idx8 = (tid + j*512) * 8;
        int s_ = idx8 >> 5, d_ = idx8 & 31;
        short8 v = *(const short8*)(Ka + base + idx8);
        *(short8*)(&Ks[s_*40 + d_]) = v;
    }
    #pragma unroll
    for (int j = 0; j < 2; ++j) {
        int idx8 = (tid + j*512) * 8;
        int d_ = idx8 >> 8, s0 = idx8 & 255;
        short8 v = *(const short8*)(Va + base + idx8);
        *(short8*)(&Vs[d_*264 + s0]) = v;
    }
    __syncthreads();

    const float* bth = bt + (size_t)h * 65536;
    const float nrmv = 0.17677669529663687f;

    #pragma unroll
    for (int qq = 0; qq < 2; ++qq) {
        int qt = w*2 + qq;                 // 0..15
        int qrow = qt * 16;
        short8 qf = *(const short8*)(Qa + base + (size_t)(qrow + c)*32 + g*8);
        const float* btt = bth + (size_t)qt*4096 + (c*4 + g)*4;

        f32x4 o0 = 0.0f, o1 = 0.0f;
        float sum = 0.f;
        __builtin_amdgcn_s_setprio(1);
        #pragma unroll
        for (int t = 0; t < 8; ++t) {
            int n0 = 2*t, n1 = 2*t + 1;
            short8 kf0 = *(const short8*)(&Ks[(n0*16 + c)*40 + g*8]);
            short8 kf1 = *(const short8*)(&Ks[(n1*16 + c)*40 + g*8]);
            f32x4 bv0 = *(const f32x4*)(btt + n0*256);
            f32x4 bv1 = *(const f32x4*)(btt + n1*256);
            f32x4 z = 0.0f;
            f32x4 s0 = __builtin_amdgcn_mfma_f32_16x16x32_bf16(kf0, qf, z, 0, 0, 0);
            f32x4 s1 = __builtin_amdgcn_mfma_f32_16x16x32_bf16(kf1, qf, z, 0, 0, 0);
            float e0 = __expf(fmaf(s0[0], nrmv, bv0[0]));
            float e1 = __expf(fmaf(s0[1], nrmv, bv0[1]));
            float e2 = __expf(fmaf(s0[2], nrmv, bv0[2]));
            float e3 = __expf(fmaf(s0[3], nrmv, bv0[3]));
            float e4 = __expf(fmaf(s1[0], nrmv, bv1[0]));
            float e5 = __expf(fmaf(s1[1], nrmv, bv1[1]));
            float e6 = __expf(fmaf(s1[2], nrmv, bv1[2]));
            float e7 = __expf(fmaf(s1[3], nrmv, bv1[3]));
            sum += ((e0+e1)+(e2+e3)) + ((e4+e5)+(e6+e7));
            u32x4 aw;
            aw[0] = pack2(e0, e1); aw[1] = pack2(e2, e3);
            aw[2] = pack2(e4, e5); aw[3] = pack2(e6, e7);
            short8 pfrag = __builtin_bit_cast(short8, aw);
            short8 va0 = *(const short8*)(&Vs[(c)*264      + t*32 + g*8]);
            short8 va1 = *(const short8*)(&Vs[(16 + c)*264 + t*32 + g*8]);
            o0 = __builtin_amdgcn_mfma_f32_16x16x32_bf16(va0, pfrag, o0, 0, 0, 0);
            o1 = __builtin_amdgcn_mfma_f32_16x16x32_bf16(va1, pfrag, o1, 0, 0, 0);
        }
        __builtin_amdgcn_s_setprio(0);
        sum += __shfl_xor(sum, 16);
        sum += __shfl_xor(sum, 32);
        float inv = 1.0f / sum;

        size_t orow = ((size_t)(r*256 + qrow + c)) * 256 + h*32 + 8*g;
        u16x8 gv = *(const u16x8*)(G + orow);
        u16x8 st;
        #pragma unroll
        for (int i = 0; i < 4; ++i) {
            st[i]     = (unsigned short)bfbits(o0[i] * inv * bf2f(gv[i]));
            st[i + 4] = (unsigned short)bfbits(o1[i] * inv * bf2f(gv[i + 4]));
        }
        *(u16x8*)(og + orow) = st;
    }
}

// ---------- oproj K-loop (As: 64x256 swizzled tile, swapped, depth-2 prefetch) ----------
__device__ __forceinline__ void proj_mfma_loop_swap(
    const unsigned short* As, const unsigned short* Wt,
    int col0, int c, int g, f32x4 acc[4][4])
{
    short8 pb[2][4];
    #pragma unroll
    for (int s = 0; s < 2; ++s)
        #pragma unroll
        for (int n = 0; n < 4; ++n)
            pb[s][n] = *(const short8*)(Wt + (size_t)(col0 + n*16 + c) * 256 + s*32 + g*8);

    __builtin_amdgcn_s_setprio(1);
    #pragma unroll
    for (int step = 0; step < 8; ++step) {
        short8 b[4];
        #pragma unroll
        for (int n = 0; n < 4; ++n) b[n] = pb[step & 1][n];
        if (step < 6) {
            int koff = (step + 2) * 32 + g * 8;
            #pragma unroll
            for (int n = 0; n < 4; ++n)
                pb[step & 1][n] = *(const short8*)(Wt + (size_t)(col0 + n*16 + c) * 256 + koff);
        }
        short8 a[4];
        #pragma unroll
        for (int m = 0; m < 4; ++m) {
            int row = m * 16 + c;
            int off = row * 512 + ((step * 64 + g * 16) ^ ((row & 31) << 4));
            a[m] = *(const short8*)((const char*)As + off);
        }
        #pragma unroll
        for (int m = 0; m < 4; ++m)
            #pragma unroll
            for (int n = 0; n < 4; ++n)
                acc[m][n] = __builtin_amdgcn_mfma_f32_16x16x32_bf16(b[n], a[m], acc[m][n], 0, 0, 0);
    }
    __builtin_amdgcn_s_setprio(0);
}

// ---------- kernel 3: output projection (LDS-staged og, swapped MFMA) ----------
__global__ __launch_bounds__(256) void oproj_kernel(
    const unsigned short* __restrict__ og, const unsigned short* __restrict__ wt_o,
    const float* __restrict__ bo, float* __restrict__ out)
{
    __shared__ __align__(16) unsigned short As[64 * 256];

    int row0 = blockIdx.x * 64;
    int tid = threadIdx.x;
    int lane = tid & 63;
    int c = lane & 15, g = lane >> 4;
    int col0 = (tid >> 6) * 64;

    #pragma unroll
    for (int j = 0; j < 8; ++j) {
        int idx = tid * 8 + j * 2048;
        int row = idx >> 8;
        int colB = (idx & 255) * 2;
        short8 v = *(const short8*)(og + (size_t)(row0 + row) * 256 + (idx & 255));
        int off = row * 512 + (colB ^ ((row & 31) << 4));
        *(short8*)((char*)As + off) = v;
    }
    __syncthreads();

    f32x4 acc[4][4];
    #pragma unroll
    for (int m = 0; m < 4; ++m)
        #pragma unroll
        for (int n = 0; n < 4; ++n)
            acc[m][n] = 0.0f;

    proj_mfma_loop_swap(As, wt_o, col0, c, g, acc);

    #pragma unroll
    for (int n = 0; n < 4; ++n) {
        int colb = col0 + n * 16 + 4 * g;
        f32x4 bov = *(const f32x4*)(bo + colb);
        #pragma unroll
        for (int m = 0; m < 4; ++m) {
            int row = row0 + m * 16 + c;
            f32x4 st = acc[m][n] + bov;
            *(f32x4*)(out + (size_t)row * 256 + colb) = st;
        }
    }
}

extern "C" void kernel_launch(void* const* d_in, const int* in_sizes, int n_in,
                              void* d_out, int out_size, void* d_ws, size_t ws_size,
                              hipStream_t stream) {
    const float* qx   = (const float*)d_in[0];
    const float* kx   = (const float*)d_in[1];
    const float* vx   = (const float*)d_in[2];
    const float* bias = (const float*)d_in[3];
    const float* Wq   = (const float*)d_in[4];
    const float* Wk   = (const float*)d_in[5];
    const float* Wv   = (const float*)d_in[6];
    const float* Wo   = (const float*)d_in[7];
    const float* bo   = (const float*)d_in[8];
    const float* Wg   = (const float*)d_in[9];
    const float* bg   = (const float*)d_in[10];

    uint8_t* ws = (uint8_t*)d_ws;
    unsigned short* wt = (unsigned short*)ws;                         // 640 KB
    unsigned short* Qa = (unsigned short*)(ws + (1u<<20));
    unsigned short* Ka = (unsigned short*)(ws + (1u<<20) + 1u*(1u<<24));
    unsigned short* Va = (unsigned short*)(ws + (1u<<20) + 2u*(1u<<24));
    unsigned short* G  = (unsigned short*)(ws + (1u<<20) + 3u*(1u<<24));
    unsigned short* og = (unsigned short*)(ws + (1u<<20) + 4u*(1u<<24));
    float*          bt = (float*)        (ws + (1u<<20) + 5u*(1u<<24)); // 2 MB

    hipLaunchKernelGGL(prep_kernel, dim3(208), dim3(256), 0, stream,
                       Wq, Wk, Wv, Wg, Wo, wt, bias, bt);
    hipLaunchKernelGGL(proj_kernel, dim3(512), dim3(512), 0, stream,
                       qx, kx, vx, bg, wt, Qa, Ka, Va, G);
    hipLaunchKernelGGL(attn_kernel, dim3(1024), dim3(512), 0, stream,
                       Qa, Ka, Va, G, bt, og);
    hipLaunchKernelGGL(oproj_kernel, dim3(512), dim3(256), 0, stream,
                       og, wt + 4*65536, bo, (float*)d_out);
}